// Round 15
// baseline (426.088 us; speedup 1.0000x reference)
//
#include <hip/hip_runtime.h>

#define B_ 16
#define S_ 12
#define N_ 325
#define E_ 2600
#define CIN_ 32
#define H_ 64
#define HEADS_ 4
#define COUT_ 12
#define BS_ (B_*S_)          // 192
#define ROWS_ (BS_*N_)       // 62400
#define EN_ (E_+N_)          // 2925
#define QK_ 256
#define HB_ (B_/2)           // 8 b per half
#define HBS_ (BS_/2)         // 96
#define HROWS_ (ROWS_/2)     // 31200

__device__ __forceinline__ int swz8(int bid, int cpx) {
  return (bid & 7) * cpx + (bid >> 3);   // grid must be multiple of 8
}

// ---------------- degree / norm / CSR pointers ----------------
__global__ void k_deg(const int* __restrict__ ei, int* __restrict__ ptr_gcn,
                      int* __restrict__ ptr_att, float* __restrict__ dinv) {
  __shared__ int cnt[N_];
  for (int i = threadIdx.x; i < N_; i += blockDim.x) cnt[i] = 0;
  __syncthreads();
  for (int e = threadIdx.x; e < E_; e += blockDim.x)
    atomicAdd(&cnt[ei[E_ + e]], 1);   // col = target
  __syncthreads();
  for (int n = threadIdx.x; n < N_; n += blockDim.x)
    dinv[n] = rsqrtf((float)(cnt[n] + 1));
  if (threadIdx.x == 0) {
    int a = 0, g = 0;
    for (int n = 0; n < N_; n++) {
      ptr_att[n] = a; ptr_gcn[n] = g;
      a += cnt[n]; g += cnt[n] + 1;   // gcn bucket has +1 self-loop slot
    }
    ptr_att[N_] = a; ptr_gcn[N_] = g;
  }
}

// ---------------- deterministic CSR fill (stable rank) ----------------
__global__ void k_fill(const int* __restrict__ ei, const int* __restrict__ ptr_gcn,
                       const int* __restrict__ ptr_att, const float* __restrict__ dinv,
                       int* __restrict__ gcn_src, float* __restrict__ gcn_w,
                       int* __restrict__ att_src) {
  __shared__ int cols[E_];
  for (int i = threadIdx.x; i < E_; i += blockDim.x) cols[i] = ei[E_ + i];
  __syncthreads();
  int e = blockIdx.x * blockDim.x + threadIdx.x;
  if (e >= EN_) return;
  int t = (e < E_) ? cols[e] : (e - E_);
  int s = (e < E_) ? ei[e]   : (e - E_);
  int lim = (e < E_) ? e : E_;
  int rank = 0;
  for (int j = 0; j < lim; j++) rank += (cols[j] == t);
  int pos = ptr_gcn[t] + rank;
  gcn_src[pos] = s;
  gcn_w[pos] = dinv[s] * dinv[t];
  if (e < E_) att_src[ptr_att[t] + rank] = s;
}

// ---------------- setup: AB, cd, Wkt (=G_h^T packed), vvec, c4, zero256 ----------------
// blocks 0..239: AB ; 240: cd ; 241..304: Wkt ; 305: vvec + c4 + zero256
__global__ void k_abcd(const float* __restrict__ Wv, const float* __restrict__ Wsm,
                       const float* __restrict__ Wl, const float* __restrict__ bl,
                       const float* __restrict__ bsv, const float* __restrict__ bvv,
                       const float* __restrict__ Wq, const float* __restrict__ bq,
                       const float* __restrict__ Wk, const float* __restrict__ bk,
                       float* __restrict__ AB, float* __restrict__ cd,
                       float* __restrict__ Wkt, float* __restrict__ vc,
                       float* __restrict__ zero256) {
  int t = threadIdx.x;
  if (blockIdx.x < 240) {
    int s = blockIdx.x / 20, dblk = blockIdx.x % 20;
    int dl = t >> 4, co = t & 15;
    int d = dblk * 16 + dl;             // 0..319
    float acc = 0.f;
    if (co < 12) {
      if (d < 256) {
        int h = d >> 6, dd = d & 63;
        for (int j = 0; j < 64; j++)
          acc += Wv[dd * 256 + h * 64 + j] * Wl[(size_t)(s * 256 + h * 64 + j) * 12 + co];
      } else {
        int d0 = d - 256;
        for (int J = 0; J < 256; J++)
          acc += Wsm[d0 * 256 + J] * Wl[(size_t)(s * 256 + J) * 12 + co];
      }
    }
    AB[((size_t)s * 320 + d) * 16 + co] = acc;
  } else if (blockIdx.x == 240) {
    __shared__ float red[2][16][17];
    int co = t & 15, chunk = t >> 4;
    float c = 0.f, dv = 0.f;
    if (co < 12) {
      for (int J = chunk * 192; J < chunk * 192 + 192; J++) {
        float wl = Wl[(size_t)J * 12 + co];
        c  += bsv[J & 255] * wl;
        dv += bvv[J & 255] * wl;
      }
    }
    red[0][chunk][co] = c;
    red[1][chunk][co] = dv;
    __syncthreads();
    if (t < 16) {
      float s0 = 0.f;
      for (int ch = 0; ch < 16; ch++) s0 += red[0][ch][t];
      cd[t] = s0 + ((t < 12) ? bl[t] : 0.f);
    } else if (t < 32) {
      int co2 = t - 16;
      float s1 = 0.f;
      for (int ch = 0; ch < 16; ch++) s1 += red[1][ch][co2];
      cd[16 + co2] = s1;
    }
  } else if (blockIdx.x < 305) {
    // Wkt[e][h*64+d] = G_h[d][e] = sum_i Wq[d][h*64+i] * Wk[e][h*64+i]
    int idx = (blockIdx.x - 241) * 256 + t;    // 0..16383
    int e = idx >> 8, col = idx & 255;
    int h = col >> 6, d = col & 63;
    float acc = 0.f;
    const float* wqr = Wq + (size_t)d * QK_ + h * 64;
    const float* wkr = Wk + (size_t)e * QK_ + h * 64;
#pragma unroll 8
    for (int i = 0; i < 64; i++) acc += wqr[i] * wkr[i];
    Wkt[(size_t)e * QK_ + col] = acc;
  } else {
    // vvec[h*64+e] = sum_i Wk[e][h*64+i] * bq[h*64+i] ; vc[256..259] = c_h ; zero256
    int h = t >> 6, e = t & 63;
    float acc = 0.f;
    const float* wkr = Wk + (size_t)e * QK_ + h * 64;
    const float* bqr = bq + h * 64;
#pragma unroll 8
    for (int i = 0; i < 64; i++) acc += wkr[i] * bqr[i];
    vc[t] = acc;
    if (t < 4) {
      float cc = 0.f;
      for (int i = 0; i < 64; i++) cc += bq[t * 64 + i] * bk[t * 64 + i];
      vc[256 + t] = cc;
    }
    zero256[t] = 0.f;
  }
}

// ---------------- GCN aggregation (SpMM), 4-way unrolled independent gathers ----------------
template<int K>
__global__ __launch_bounds__(256) void k_agg(const float* __restrict__ hin,
    const int* __restrict__ ptr, const int* __restrict__ src,
    const float* __restrict__ wgt, float* __restrict__ ag) {
  int wid = threadIdx.x >> 6, lane = threadIdx.x & 63;
  int n = blockIdx.x * 4 + wid;
  int bs = blockIdx.y;
  if (n >= N_ || (K != 64 && lane >= K)) return;
  int p0 = ptr[n], p1 = ptr[n + 1];
  const float* base = hin + (size_t)bs * N_ * K;
  float a0 = 0.f, a1 = 0.f, a2 = 0.f, a3 = 0.f;
  int e = p0;
  for (; e + 4 <= p1; e += 4) {
    a0 += wgt[e]     * base[src[e]     * K + lane];
    a1 += wgt[e + 1] * base[src[e + 1] * K + lane];
    a2 += wgt[e + 2] * base[src[e + 2] * K + lane];
    a3 += wgt[e + 3] * base[src[e + 3] * K + lane];
  }
  for (; e < p1; ++e) a0 += wgt[e] * base[src[e] * K + lane];
  ag[((size_t)bs * N_ + n) * K + lane] = (a0 + a1) + (a2 + a3);
}

// ---------------- tiled GEMM: C[M x 64-slice] = A[M x K] @ W[:,c0:c0+64] + bias (opt relu) ----
template<int K, bool RELU>
__global__ __launch_bounds__(256) void k_gemm(
    const float* __restrict__ A, int M,
    const float* __restrict__ W0, const float* __restrict__ b0, float* __restrict__ C0,
    const float* __restrict__ W1, const float* __restrict__ b1, float* __restrict__ C1,
    int wstride, int cstride, int nct) {
  __shared__ float Ast[K][136];
  __shared__ float Wsh[K][68];
  int t = threadIdx.x;
  int ct = blockIdx.y;
  const float* W   = (ct < nct) ? W0 : W1;
  const float* bia = (ct < nct) ? b0 : b1;
  float* C         = (ct < nct) ? C0 : C1;
  int c0 = (ct & (nct - 1)) * 64;          // nct is 1 or 4 (power of 2)
  for (int i = t; i < K * 64; i += 256)
    Wsh[i >> 6][i & 63] = W[(size_t)(i >> 6) * wstride + c0 + (i & 63)];
  int r0 = blockIdx.x * 128;
  constexpr int KQ = K / 4;
#pragma unroll
  for (int it = 0; it < KQ / 2; ++it) {    // 128*KQ/256 iters
    int idx = it * 256 + t;
    int dq = idx >> 7, rl = idx & 127;
    int ar = min(r0 + rl, M - 1);
    float4 v = *(const float4*)(A + (size_t)ar * K + dq * 4);
    Ast[dq * 4 + 0][rl] = v.x; Ast[dq * 4 + 1][rl] = v.y;
    Ast[dq * 4 + 2][rl] = v.z; Ast[dq * 4 + 3][rl] = v.w;
  }
  __syncthreads();
  int tr = t >> 4, tc = t & 15;            // rows tr*8..+7, cols tc*4..+3
  float acc[8][4];
#pragma unroll
  for (int i = 0; i < 8; i++)
#pragma unroll
    for (int j = 0; j < 4; j++) acc[i][j] = 0.f;
#pragma unroll 8
  for (int k = 0; k < K; k++) {
    float4 w4 = *(const float4*)&Wsh[k][tc * 4];
    float4 a0 = *(const float4*)&Ast[k][tr * 8];
    float4 a1 = *(const float4*)&Ast[k][tr * 8 + 4];
    const float av[8] = {a0.x, a0.y, a0.z, a0.w, a1.x, a1.y, a1.z, a1.w};
#pragma unroll
    for (int i = 0; i < 8; i++) {
      acc[i][0] += av[i] * w4.x; acc[i][1] += av[i] * w4.y;
      acc[i][2] += av[i] * w4.z; acc[i][3] += av[i] * w4.w;
    }
  }
  float4 b4 = *(const float4*)&bia[c0 + tc * 4];
#pragma unroll
  for (int i = 0; i < 8; i++) {
    int row = r0 + tr * 8 + i;
    if (row < M) {
      float4 o = make_float4(acc[i][0] + b4.x, acc[i][1] + b4.y,
                             acc[i][2] + b4.z, acc[i][3] + b4.w);
      if (RELU) {
        o.x = fmaxf(o.x, 0.f); o.y = fmaxf(o.y, 0.f);
        o.z = fmaxf(o.z, 0.f); o.w = fmaxf(o.w, 0.f);
      }
      *(float4*)(C + (size_t)row * cstride + c0 + tc * 4) = o;
    }
  }
}

// ---------------- beta: bb[row][h] = xt_row . vvec_h + c_h ----------------
__global__ __launch_bounds__(256) void k_beta(const float* __restrict__ xt,
    const float* __restrict__ vc, float* __restrict__ bb) {
  __shared__ float vs[260];
  int t = threadIdx.x;
  vs[t] = vc[t];
  if (t < 4) vs[256 + t] = vc[256 + t];
  __syncthreads();
  int row = blockIdx.x * 64 + (t >> 2), h = t & 3;
  const float4* xr = (const float4*)(xt + (size_t)row * 64);
  const float4* vr = (const float4*)&vs[h * 64];
  float d0 = 0.f, d1 = 0.f;
#pragma unroll
  for (int j = 0; j < 16; j += 2) {
    float4 xa = xr[j], va = vr[j];
    float4 xb2 = xr[j + 1], vb = vr[j + 1];
    d0 += xa.x * va.x + xa.y * va.y + xa.z * va.z + xa.w * va.w;
    d1 += xb2.x * vb.x + xb2.y * vb.y + xb2.z * vb.z + xb2.w * vb.w;
  }
  bb[(size_t)row * 4 + h] = d0 + d1 + vs[256 + h];
}

// ---------------- fused multi-head attention (R12 body + LDS w-broadcast PV) ----------------
// logit = (xt_t . kt_s,h + beta_s,h) / 8 (per-target constant dropped: softmax-invariant)
// PV: w staged in wave-local LDS -> one broadcast b128 per edge instead of 4 bpermutes.
__global__ void k_attn4(const float* __restrict__ kt, const float* __restrict__ xt,
                        const float* __restrict__ bb, const int* __restrict__ ptr,
                        const int* __restrict__ src, int half,
                        float* __restrict__ z) {
  __shared__ float xs[4][68];
  __shared__ float wbuf[4][64];
  int bid = swz8(blockIdx.x, 975);             // 7800/8
  int wid = threadIdx.x >> 6, lane = threadIdx.x & 63;
  int g = bid * 4 + wid;
  int n = g % N_, bsl = g / N_;
  int p0 = ptr[n], p1 = ptr[n + 1];
  const float* xb = xt + ((size_t)half * HBS_ + bsl) * N_ * 64;
  xs[wid][lane] = xb[(size_t)n * 64 + lane];   // same-wave write->read, no barrier
  int h = lane & 3, el = lane >> 2;
  const float* kb = kt + (size_t)bsl * N_ * QK_;
  const float* bbb = bb + ((size_t)half * HROWS_ + (size_t)bsl * N_) * 4;
  const float4* x4 = reinterpret_cast<const float4*>(&xs[wid][0]);
  float m = -INFINITY, den = 0.f;
  float zacc[4] = {0.f, 0.f, 0.f, 0.f};
  for (int base = p0; base < p1; base += 16) {
    int slot = base + el;
    bool valid = slot < p1;
    int sidx = valid ? src[slot] : 0;
    float logit = -INFINITY;
    if (valid) {
      const float4* k4 = reinterpret_cast<const float4*>(kb + (size_t)sidx * QK_ + h * 64);
      float d0 = 0.f, d1 = 0.f;
#pragma unroll
      for (int j = 0; j < 16; j += 2) {
        float4 ka = k4[j], kb2 = k4[j + 1];
        float4 xa = x4[j], xb2 = x4[j + 1];
        d0 += xa.x * ka.x + xa.y * ka.y + xa.z * ka.z + xa.w * ka.w;
        d1 += xb2.x * kb2.x + xb2.y * kb2.y + xb2.z * kb2.z + xb2.w * kb2.w;
      }
      logit = (d0 + d1 + bbb[sidx * 4 + h]) * 0.125f;   // 1/sqrt(64)
    }
    float cm = logit;
#pragma unroll
    for (int o = 4; o < 64; o <<= 1) cm = fmaxf(cm, __shfl_xor(cm, o));
    float mnew = fmaxf(m, cm);
    float scale = __expf(m - mnew);            // first chunk: exp(-inf)=0
    float w = valid ? __expf(logit - mnew) : 0.f;
    float wsum = w;
#pragma unroll
    for (int o = 4; o < 64; o <<= 1) wsum += __shfl_xor(wsum, o);
    den = den * scale + wsum;
    wbuf[wid][lane] = w;                       // same-wave DS order: visible below
#pragma unroll
    for (int h2 = 0; h2 < 4; h2++) zacc[h2] *= __shfl(scale, h2);
    int cnt = min(16, p1 - base);
    for (int e2 = 0; e2 < cnt; e2++) {
      int s_e = __shfl(sidx, e2 * 4);
      float xv = xb[(size_t)s_e * 64 + lane];
      float4 w4 = *(const float4*)&wbuf[wid][e2 * 4];  // broadcast, conflict-free
      zacc[0] += w4.x * xv; zacc[1] += w4.y * xv;
      zacc[2] += w4.z * xv; zacc[3] += w4.w * xv;
    }
    m = mnew;
  }
  bool ok = p1 > p0;
#pragma unroll
  for (int h2 = 0; h2 < 4; h2++) {
    float dh = __shfl(den, h2);
    z[(size_t)g * QK_ + h2 * 64 + lane] = ok ? zacc[h2] / (dh + 1e-16f) : 0.f;
  }
}

// ---------------- thin GEMM: partial[row][co] = [z|xt]_row(320) @ AB_s(320x12) ----------------
__global__ __launch_bounds__(256) void k_fin(const float* __restrict__ z,
    const float* __restrict__ xt, const float* __restrict__ AB, int half,
    float* __restrict__ partial) {
  __shared__ float Zs[32][327];
  __shared__ float ABs[320][16];
  int t = threadIdx.x;
  int bs_loc = blockIdx.x;           // 0..95
  int s = bs_loc % 12;
  int n0 = blockIdx.y * 32;
  const float4* ABg = (const float4*)(AB + (size_t)s * 320 * 16);
  for (int i = t; i < 320 * 4; i += 256) ((float4*)ABs)[i] = ABg[i];
  for (int i = t; i < 2560; i += 256) {
    int rl = i / 80, dq = i % 80;
    int n = min(n0 + rl, N_ - 1);
    size_t row = (size_t)bs_loc * N_ + n;
    float4 v;
    if (dq < 64) v = ((const float4*)z)[row * 64 + dq];
    else v = ((const float4*)xt)[((size_t)half * HROWS_ + row) * 16 + (dq - 64)];
    int d0 = dq * 4;
    Zs[rl][d0] = v.x; Zs[rl][d0 + 1] = v.y; Zs[rl][d0 + 2] = v.z; Zs[rl][d0 + 3] = v.w;
  }
  __syncthreads();
  float acc[4][4];
#pragma unroll
  for (int i = 0; i < 4; i++)
#pragma unroll
    for (int j = 0; j < 4; j++) acc[i][j] = 0.f;
  int rg = t & 7, tmp = t >> 3;
  int cg = tmp % 3, dc = tmp / 3;
  if (dc < 10) {
    int dbase = dc * 32;
    for (int dd = 0; dd < 32; dd++) {
      int d = dbase + dd;
      float4 ab = *(const float4*)&ABs[d][cg * 4];
      float a0 = Zs[rg * 4 + 0][d], a1 = Zs[rg * 4 + 1][d];
      float a2 = Zs[rg * 4 + 2][d], a3 = Zs[rg * 4 + 3][d];
      acc[0][0] += a0 * ab.x; acc[0][1] += a0 * ab.y; acc[0][2] += a0 * ab.z; acc[0][3] += a0 * ab.w;
      acc[1][0] += a1 * ab.x; acc[1][1] += a1 * ab.y; acc[1][2] += a1 * ab.z; acc[1][3] += a1 * ab.w;
      acc[2][0] += a2 * ab.x; acc[2][1] += a2 * ab.y; acc[2][2] += a2 * ab.z; acc[2][3] += a2 * ab.w;
      acc[3][0] += a3 * ab.x; acc[3][1] += a3 * ab.y; acc[3][2] += a3 * ab.z; acc[3][3] += a3 * ab.w;
    }
  }
  __syncthreads();
  float* red = &Zs[0][0];
  if (dc < 10) {
    int base = (((rg * 3 + cg) * 10) + dc) * 16;
#pragma unroll
    for (int i = 0; i < 4; i++)
      *(float4*)&red[base + i * 4] = make_float4(acc[i][0], acc[i][1], acc[i][2], acc[i][3]);
  }
  __syncthreads();
  for (int o = t; o < 384; o += 256) {
    int r = o / 12, co = o % 12;
    int rg2 = r >> 2, i2 = r & 3, cg2 = co >> 2, j2 = co & 3;
    float s0 = 0.f;
#pragma unroll
    for (int d2 = 0; d2 < 10; d2++)
      s0 += red[(((rg2 * 3 + cg2) * 10) + d2) * 16 + i2 * 4 + j2];
    int n = n0 + r;
    if (n < N_)
      partial[((size_t)half * HROWS_ + (size_t)bs_loc * N_ + n) * 12 + co] = s0;
  }
}

// ---------------- y = sum_s partial + cvec + 1{deg>0} dvec ----------------
__global__ void k_red(const float* __restrict__ partial, const float* __restrict__ cd,
                      const int* __restrict__ ptr, float* __restrict__ y) {
  int tg = blockIdx.x * 256 + threadIdx.x;
  if (tg >= B_ * N_ * 12) return;
  int bn = tg / 12, co = tg % 12;
  int b = bn / N_, n = bn % N_;
  float acc = cd[co];
  if (ptr[n + 1] > ptr[n]) acc += cd[16 + co];
  for (int s = 0; s < 12; s++)
    acc += partial[(((size_t)(b * 12 + s)) * N_ + n) * 12 + co];
  y[(size_t)bn * 12 + co] = acc;
}

extern "C" void kernel_launch(void* const* d_in, const int* in_sizes, int n_in,
                              void* d_out, int out_size, void* d_ws, size_t ws_size,
                              hipStream_t stream) {
  const float* x   = (const float*)d_in[0];
  const int*   ei  = (const int*)d_in[1];
  const float* Wg[4] = {(const float*)d_in[2], (const float*)d_in[4],
                        (const float*)d_in[6], (const float*)d_in[8]};
  const float* bg[4] = {(const float*)d_in[3], (const float*)d_in[5],
                        (const float*)d_in[7], (const float*)d_in[9]};
  const float* Wq = (const float*)d_in[10]; const float* bq = (const float*)d_in[11];
  const float* Wk = (const float*)d_in[12]; const float* bk = (const float*)d_in[13];
  const float* Wv = (const float*)d_in[14]; const float* bv = (const float*)d_in[15];
  const float* Ws = (const float*)d_in[16]; const float* bs = (const float*)d_in[17];
  const float* Wl = (const float*)d_in[18]; const float* bl = (const float*)d_in[19];
  float* y = (float*)d_out;

  char* p = (char*)d_ws;
  auto alloc = [&](size_t bytes) {
    char* r = p;
    p += (bytes + 255) & ~(size_t)255;
    return r;
  };
  float* dinv    = (float*)alloc(N_ * 4);
  int*   ptr_gcn = (int*)alloc((N_ + 1) * 4);
  int*   ptr_att = (int*)alloc((N_ + 1) * 4);
  int*   gcn_src = (int*)alloc(EN_ * 4);
  float* gcn_w   = (float*)alloc(EN_ * 4);
  int*   att_src = (int*)alloc(E_ * 4);
  float* AB      = (float*)alloc((size_t)12 * 320 * 16 * 4);  // 245 KB
  float* cd      = (float*)alloc(32 * 4);
  float* Wkt     = (float*)alloc((size_t)64 * QK_ * 4);       // 64 KB
  float* vc      = (float*)alloc(260 * 4);
  float* zero256 = (float*)alloc(256 * 4);
  float* bb      = (float*)alloc((size_t)ROWS_ * 4 * 4);      // 1 MB
  float* ag = (float*)alloc((size_t)ROWS_ * H_ * 4);       // 16 MB (agg scratch)
  float* h0 = (float*)alloc((size_t)ROWS_ * H_ * 4);       // 16 MB
  float* h1 = (float*)alloc((size_t)ROWS_ * H_ * 4);       // 16 MB (xt)
  float* ktb = (float*)alloc((size_t)HROWS_ * QK_ * 4);    // 32 MB (per half)
  float* zb  = (float*)alloc((size_t)HROWS_ * QK_ * 4);    // 32 MB (per half)
  float* partial = (float*)alloc((size_t)ROWS_ * 12 * 4);  // 3 MB
  (void)ws_size; (void)in_sizes; (void)n_in; (void)out_size;

  k_deg<<<1, 512, 0, stream>>>(ei, ptr_gcn, ptr_att, dinv);
  k_fill<<<(EN_ + 255) / 256, 256, 0, stream>>>(ei, ptr_gcn, ptr_att, dinv,
                                                gcn_src, gcn_w, att_src);
  k_abcd<<<306, 256, 0, stream>>>(Wv, Ws, Wl, bl, bs, bv, Wq, bq, Wk, bk,
                                  AB, cd, Wkt, vc, zero256);

  // GCN layers: agg (SpMM) + tiled GEMM, ping-pong x -> h0 -> h1 -> h0 -> h1
  dim3 agrid((N_ + 3) / 4, BS_);
  int mt = (ROWS_ + 127) / 128;     // 488
  k_agg<CIN_><<<agrid, 256, 0, stream>>>(x, ptr_gcn, gcn_src, gcn_w, ag);
  k_gemm<CIN_, true><<<dim3(mt, 1), 256, 0, stream>>>(ag, ROWS_, Wg[0], bg[0], h0,
                                                      Wg[0], bg[0], h0, 64, 64, 1);
  k_agg<H_><<<agrid, 256, 0, stream>>>(h0, ptr_gcn, gcn_src, gcn_w, ag);
  k_gemm<H_, true><<<dim3(mt, 1), 256, 0, stream>>>(ag, ROWS_, Wg[1], bg[1], h1,
                                                    Wg[1], bg[1], h1, 64, 64, 1);
  k_agg<H_><<<agrid, 256, 0, stream>>>(h1, ptr_gcn, gcn_src, gcn_w, ag);
  k_gemm<H_, true><<<dim3(mt, 1), 256, 0, stream>>>(ag, ROWS_, Wg[2], bg[2], h0,
                                                    Wg[2], bg[2], h0, 64, 64, 1);
  k_agg<H_><<<agrid, 256, 0, stream>>>(h0, ptr_gcn, gcn_src, gcn_w, ag);
  k_gemm<H_, true><<<dim3(mt, 1), 256, 0, stream>>>(ag, ROWS_, Wg[3], bg[3], h1,
                                                    Wg[3], bg[3], h1, 64, 64, 1);

  // beta over all rows (depends only on xt = h1)
  k_beta<<<ROWS_ / 64, 256, 0, stream>>>(h1, vc, bb);

  int mth = (HROWS_ + 127) / 128;   // 244
  for (int half = 0; half < 2; half++) {
    const float* xh = h1 + (size_t)half * HROWS_ * 64;
    // kt = xt @ Wkt  (4 head-slices)
    k_gemm<H_, false><<<dim3(mth, 4), 256, 0, stream>>>(xh, HROWS_, Wkt, zero256, ktb,
                                                        Wkt, zero256, ktb, QK_, QK_, 4);
    k_attn4<<<HROWS_ / 4, 256, 0, stream>>>(ktb, h1, bb, ptr_att, att_src, half, zb);
    k_fin<<<dim3(HBS_, 11), 256, 0, stream>>>(zb, h1, AB, half, partial);
  }
  k_red<<<(B_ * N_ * 12 + 255) / 256, 256, 0, stream>>>(partial, cd, ptr_att, y);
}

// Round 16
// 396.625 us; speedup vs baseline: 1.0743x; 1.0743x over previous
//
#include <hip/hip_runtime.h>

#define B_ 16
#define S_ 12
#define N_ 325
#define E_ 2600
#define CIN_ 32
#define H_ 64
#define HEADS_ 4
#define COUT_ 12
#define BS_ (B_*S_)          // 192
#define ROWS_ (BS_*N_)       // 62400
#define EN_ (E_+N_)          // 2925
#define QK_ 256
#define HB_ (B_/2)           // 8 b per half
#define HBS_ (BS_/2)         // 96
#define HROWS_ (ROWS_/2)     // 31200
#define NCH_ 82              // ceil(N/4)

__device__ __forceinline__ int swz8(int bid, int cpx) {
  return (bid & 7) * cpx + (bid >> 3);   // grid must be multiple of 8
}

// ---------------- degree / norm / CSR pointers ----------------
__global__ void k_deg(const int* __restrict__ ei, int* __restrict__ ptr_gcn,
                      int* __restrict__ ptr_att, float* __restrict__ dinv) {
  __shared__ int cnt[N_];
  for (int i = threadIdx.x; i < N_; i += blockDim.x) cnt[i] = 0;
  __syncthreads();
  for (int e = threadIdx.x; e < E_; e += blockDim.x)
    atomicAdd(&cnt[ei[E_ + e]], 1);   // col = target
  __syncthreads();
  for (int n = threadIdx.x; n < N_; n += blockDim.x)
    dinv[n] = rsqrtf((float)(cnt[n] + 1));
  if (threadIdx.x == 0) {
    int a = 0, g = 0;
    for (int n = 0; n < N_; n++) {
      ptr_att[n] = a; ptr_gcn[n] = g;
      a += cnt[n]; g += cnt[n] + 1;   // gcn bucket has +1 self-loop slot
    }
    ptr_att[N_] = a; ptr_gcn[N_] = g;
  }
}

// ---------------- deterministic CSR fill (stable rank) ----------------
__global__ void k_fill(const int* __restrict__ ei, const int* __restrict__ ptr_gcn,
                       const int* __restrict__ ptr_att, const float* __restrict__ dinv,
                       int* __restrict__ gcn_src, float* __restrict__ gcn_w,
                       int* __restrict__ att_src) {
  __shared__ int cols[E_];
  for (int i = threadIdx.x; i < E_; i += blockDim.x) cols[i] = ei[E_ + i];
  __syncthreads();
  int e = blockIdx.x * blockDim.x + threadIdx.x;
  if (e >= EN_) return;
  int t = (e < E_) ? cols[e] : (e - E_);
  int s = (e < E_) ? ei[e]   : (e - E_);
  int lim = (e < E_) ? e : E_;
  int rank = 0;
  for (int j = 0; j < lim; j++) rank += (cols[j] == t);
  int pos = ptr_gcn[t] + rank;
  gcn_src[pos] = s;
  gcn_w[pos] = dinv[s] * dinv[t];
  if (e < E_) att_src[ptr_att[t] + rank] = s;
}

// ---------------- setup: AB, cd, Wkt (=G_h^T packed), vvec, c4, zero256 ----------------
__global__ void k_abcd(const float* __restrict__ Wv, const float* __restrict__ Wsm,
                       const float* __restrict__ Wl, const float* __restrict__ bl,
                       const float* __restrict__ bsv, const float* __restrict__ bvv,
                       const float* __restrict__ Wq, const float* __restrict__ bq,
                       const float* __restrict__ Wk, const float* __restrict__ bk,
                       float* __restrict__ AB, float* __restrict__ cd,
                       float* __restrict__ Wkt, float* __restrict__ vc,
                       float* __restrict__ zero256) {
  int t = threadIdx.x;
  if (blockIdx.x < 240) {
    int s = blockIdx.x / 20, dblk = blockIdx.x % 20;
    int dl = t >> 4, co = t & 15;
    int d = dblk * 16 + dl;             // 0..319
    float acc = 0.f;
    if (co < 12) {
      if (d < 256) {
        int h = d >> 6, dd = d & 63;
        for (int j = 0; j < 64; j++)
          acc += Wv[dd * 256 + h * 64 + j] * Wl[(size_t)(s * 256 + h * 64 + j) * 12 + co];
      } else {
        int d0 = d - 256;
        for (int J = 0; J < 256; J++)
          acc += Wsm[d0 * 256 + J] * Wl[(size_t)(s * 256 + J) * 12 + co];
      }
    }
    AB[((size_t)s * 320 + d) * 16 + co] = acc;
  } else if (blockIdx.x == 240) {
    __shared__ float red[2][16][17];
    int co = t & 15, chunk = t >> 4;
    float c = 0.f, dv = 0.f;
    if (co < 12) {
      for (int J = chunk * 192; J < chunk * 192 + 192; J++) {
        float wl = Wl[(size_t)J * 12 + co];
        c  += bsv[J & 255] * wl;
        dv += bvv[J & 255] * wl;
      }
    }
    red[0][chunk][co] = c;
    red[1][chunk][co] = dv;
    __syncthreads();
    if (t < 16) {
      float s0 = 0.f;
      for (int ch = 0; ch < 16; ch++) s0 += red[0][ch][t];
      cd[t] = s0 + ((t < 12) ? bl[t] : 0.f);
    } else if (t < 32) {
      int co2 = t - 16;
      float s1 = 0.f;
      for (int ch = 0; ch < 16; ch++) s1 += red[1][ch][co2];
      cd[16 + co2] = s1;
    }
  } else if (blockIdx.x < 305) {
    // Wkt[e][h*64+d] = G_h[d][e] = sum_i Wq[d][h*64+i] * Wk[e][h*64+i]
    int idx = (blockIdx.x - 241) * 256 + t;    // 0..16383
    int e = idx >> 8, col = idx & 255;
    int h = col >> 6, d = col & 63;
    float acc = 0.f;
    const float* wqr = Wq + (size_t)d * QK_ + h * 64;
    const float* wkr = Wk + (size_t)e * QK_ + h * 64;
#pragma unroll 8
    for (int i = 0; i < 64; i++) acc += wqr[i] * wkr[i];
    Wkt[(size_t)e * QK_ + col] = acc;
  } else {
    // vvec[h*64+e] = sum_i Wk[e][h*64+i] * bq[h*64+i] ; vc[256..259] = c_h ; zero256
    int h = t >> 6, e = t & 63;
    float acc = 0.f;
    const float* wkr = Wk + (size_t)e * QK_ + h * 64;
    const float* bqr = bq + h * 64;
#pragma unroll 8
    for (int i = 0; i < 64; i++) acc += wkr[i] * bqr[i];
    vc[t] = acc;
    if (t < 4) {
      float cc = 0.f;
      for (int i = 0; i < 64; i++) cc += bq[t * 64 + i] * bk[t * 64 + i];
      vc[256 + t] = cc;
    }
    zero256[t] = 0.f;
  }
}

// ---------------- GCN aggregation (SpMM), XCD-partitioned ----------------
// 1D grid 15744 = 8 XCDs x (24 bs x 82 n-chunks): each XCD owns 24 contiguous bs
// slices (24 x 83KB = 2MB h-data, L2-resident) -> gather hits L2, not L3.
template<int K>
__global__ __launch_bounds__(256) void k_agg(const float* __restrict__ hin,
    const int* __restrict__ ptr, const int* __restrict__ src,
    const float* __restrict__ wgt, float* __restrict__ ag) {
  int wid = threadIdx.x >> 6, lane = threadIdx.x & 63;
  int bid = blockIdx.x;                  // 15744 = 8 * 1968, 1968 = 24 * 82
  int xcd = bid & 7, sub = bid >> 3;
  int bs = xcd * 24 + sub / NCH_;        // contiguous per XCD
  int n = (sub % NCH_) * 4 + wid;
  if (n >= N_ || (K != 64 && lane >= K)) return;
  int p0 = ptr[n], p1 = ptr[n + 1];
  const float* base = hin + (size_t)bs * N_ * K;
  float a0 = 0.f, a1 = 0.f, a2 = 0.f, a3 = 0.f;
  int e = p0;
  for (; e + 4 <= p1; e += 4) {
    a0 += wgt[e]     * base[src[e]     * K + lane];
    a1 += wgt[e + 1] * base[src[e + 1] * K + lane];
    a2 += wgt[e + 2] * base[src[e + 2] * K + lane];
    a3 += wgt[e + 3] * base[src[e + 3] * K + lane];
  }
  for (; e < p1; ++e) a0 += wgt[e] * base[src[e] * K + lane];
  ag[((size_t)bs * N_ + n) * K + lane] = (a0 + a1) + (a2 + a3);
}

// ---------------- tiled GEMM: C[M x 64-slice] = A[M x K] @ W[:,c0:c0+64] + bias (opt relu) ----
template<int K, bool RELU>
__global__ __launch_bounds__(256) void k_gemm(
    const float* __restrict__ A, int M,
    const float* __restrict__ W0, const float* __restrict__ b0, float* __restrict__ C0,
    const float* __restrict__ W1, const float* __restrict__ b1, float* __restrict__ C1,
    int wstride, int cstride, int nct) {
  __shared__ float Ast[K][136];
  __shared__ float Wsh[K][68];
  int t = threadIdx.x;
  int ct = blockIdx.y;
  const float* W   = (ct < nct) ? W0 : W1;
  const float* bia = (ct < nct) ? b0 : b1;
  float* C         = (ct < nct) ? C0 : C1;
  int c0 = (ct & (nct - 1)) * 64;          // nct is 1 or 4 (power of 2)
  for (int i = t; i < K * 64; i += 256)
    Wsh[i >> 6][i & 63] = W[(size_t)(i >> 6) * wstride + c0 + (i & 63)];
  int r0 = blockIdx.x * 128;
  constexpr int KQ = K / 4;
#pragma unroll
  for (int it = 0; it < KQ / 2; ++it) {    // 128*KQ/256 iters
    int idx = it * 256 + t;
    int dq = idx >> 7, rl = idx & 127;
    int ar = min(r0 + rl, M - 1);
    float4 v = *(const float4*)(A + (size_t)ar * K + dq * 4);
    Ast[dq * 4 + 0][rl] = v.x; Ast[dq * 4 + 1][rl] = v.y;
    Ast[dq * 4 + 2][rl] = v.z; Ast[dq * 4 + 3][rl] = v.w;
  }
  __syncthreads();
  int tr = t >> 4, tc = t & 15;            // rows tr*8..+7, cols tc*4..+3
  float acc[8][4];
#pragma unroll
  for (int i = 0; i < 8; i++)
#pragma unroll
    for (int j = 0; j < 4; j++) acc[i][j] = 0.f;
#pragma unroll 8
  for (int k = 0; k < K; k++) {
    float4 w4 = *(const float4*)&Wsh[k][tc * 4];
    float4 a0 = *(const float4*)&Ast[k][tr * 8];
    float4 a1 = *(const float4*)&Ast[k][tr * 8 + 4];
    const float av[8] = {a0.x, a0.y, a0.z, a0.w, a1.x, a1.y, a1.z, a1.w};
#pragma unroll
    for (int i = 0; i < 8; i++) {
      acc[i][0] += av[i] * w4.x; acc[i][1] += av[i] * w4.y;
      acc[i][2] += av[i] * w4.z; acc[i][3] += av[i] * w4.w;
    }
  }
  float4 b4 = *(const float4*)&bia[c0 + tc * 4];
#pragma unroll
  for (int i = 0; i < 8; i++) {
    int row = r0 + tr * 8 + i;
    if (row < M) {
      float4 o = make_float4(acc[i][0] + b4.x, acc[i][1] + b4.y,
                             acc[i][2] + b4.z, acc[i][3] + b4.w);
      if (RELU) {
        o.x = fmaxf(o.x, 0.f); o.y = fmaxf(o.y, 0.f);
        o.z = fmaxf(o.z, 0.f); o.w = fmaxf(o.w, 0.f);
      }
      *(float4*)(C + (size_t)row * cstride + c0 + tc * 4) = o;
    }
  }
}

// ---------------- beta: bb[row][h] = xt_row . vvec_h + c_h ----------------
__global__ __launch_bounds__(256) void k_beta(const float* __restrict__ xt,
    const float* __restrict__ vc, float* __restrict__ bb) {
  __shared__ float vs[260];
  int t = threadIdx.x;
  vs[t] = vc[t];
  if (t < 4) vs[256 + t] = vc[256 + t];
  __syncthreads();
  int row = blockIdx.x * 64 + (t >> 2), h = t & 3;
  const float4* xr = (const float4*)(xt + (size_t)row * 64);
  const float4* vr = (const float4*)&vs[h * 64];
  float d0 = 0.f, d1 = 0.f;
#pragma unroll
  for (int j = 0; j < 16; j += 2) {
    float4 xa = xr[j], va = vr[j];
    float4 xb2 = xr[j + 1], vb = vr[j + 1];
    d0 += xa.x * va.x + xa.y * va.y + xa.z * va.z + xa.w * va.w;
    d1 += xb2.x * vb.x + xb2.y * vb.y + xb2.z * vb.z + xb2.w * vb.w;
  }
  bb[(size_t)row * 4 + h] = d0 + d1 + vs[256 + h];
}

// ---------------- fused multi-head attention (R12 body + LDS w-broadcast PV) ----------------
__global__ void k_attn4(const float* __restrict__ kt, const float* __restrict__ xt,
                        const float* __restrict__ bb, const int* __restrict__ ptr,
                        const int* __restrict__ src, int half,
                        float* __restrict__ z) {
  __shared__ float xs[4][68];
  __shared__ float wbuf[4][64];
  int bid = swz8(blockIdx.x, 975);             // 7800/8
  int wid = threadIdx.x >> 6, lane = threadIdx.x & 63;
  int g = bid * 4 + wid;
  int n = g % N_, bsl = g / N_;
  int p0 = ptr[n], p1 = ptr[n + 1];
  const float* xb = xt + ((size_t)half * HBS_ + bsl) * N_ * 64;
  xs[wid][lane] = xb[(size_t)n * 64 + lane];   // same-wave write->read, no barrier
  int h = lane & 3, el = lane >> 2;
  const float* kb = kt + ((size_t)half * HBS_ + bsl) * N_ * QK_;
  const float* bbb = bb + ((size_t)half * HROWS_ + (size_t)bsl * N_) * 4;
  const float4* x4 = reinterpret_cast<const float4*>(&xs[wid][0]);
  float m = -INFINITY, den = 0.f;
  float zacc[4] = {0.f, 0.f, 0.f, 0.f};
  for (int base = p0; base < p1; base += 16) {
    int slot = base + el;
    bool valid = slot < p1;
    int sidx = valid ? src[slot] : 0;
    float logit = -INFINITY;
    if (valid) {
      const float4* k4 = reinterpret_cast<const float4*>(kb + (size_t)sidx * QK_ + h * 64);
      float d0 = 0.f, d1 = 0.f;
#pragma unroll
      for (int j = 0; j < 16; j += 2) {
        float4 ka = k4[j], kb2 = k4[j + 1];
        float4 xa = x4[j], xb2 = x4[j + 1];
        d0 += xa.x * ka.x + xa.y * ka.y + xa.z * ka.z + xa.w * ka.w;
        d1 += xb2.x * kb2.x + xb2.y * kb2.y + xb2.z * kb2.z + xb2.w * kb2.w;
      }
      logit = (d0 + d1 + bbb[sidx * 4 + h]) * 0.125f;   // 1/sqrt(64)
    }
    float cm = logit;
#pragma unroll
    for (int o = 4; o < 64; o <<= 1) cm = fmaxf(cm, __shfl_xor(cm, o));
    float mnew = fmaxf(m, cm);
    float scale = __expf(m - mnew);            // first chunk: exp(-inf)=0
    float w = valid ? __expf(logit - mnew) : 0.f;
    float wsum = w;
#pragma unroll
    for (int o = 4; o < 64; o <<= 1) wsum += __shfl_xor(wsum, o);
    den = den * scale + wsum;
    wbuf[wid][lane] = w;                       // same-wave DS order: visible below
#pragma unroll
    for (int h2 = 0; h2 < 4; h2++) zacc[h2] *= __shfl(scale, h2);
    int cnt = min(16, p1 - base);
    for (int e2 = 0; e2 < cnt; e2++) {
      int s_e = __shfl(sidx, e2 * 4);
      float xv = xb[(size_t)s_e * 64 + lane];
      float4 w4 = *(const float4*)&wbuf[wid][e2 * 4];  // broadcast, conflict-free
      zacc[0] += w4.x * xv; zacc[1] += w4.y * xv;
      zacc[2] += w4.z * xv; zacc[3] += w4.w * xv;
    }
    m = mnew;
  }
  bool ok = p1 > p0;
#pragma unroll
  for (int h2 = 0; h2 < 4; h2++) {
    float dh = __shfl(den, h2);
    z[(size_t)g * QK_ + h2 * 64 + lane] = ok ? zacc[h2] / (dh + 1e-16f) : 0.f;
  }
}

// ---------------- thin GEMM: partial[row][co] = [z|xt]_row(320) @ AB_s(320x12) ----------------
__global__ __launch_bounds__(256) void k_fin(const float* __restrict__ z,
    const float* __restrict__ xt, const float* __restrict__ AB, int half,
    float* __restrict__ partial) {
  __shared__ float Zs[32][327];
  __shared__ float ABs[320][16];
  int t = threadIdx.x;
  int bs_loc = blockIdx.x;           // 0..95
  int s = bs_loc % 12;
  int n0 = blockIdx.y * 32;
  const float4* ABg = (const float4*)(AB + (size_t)s * 320 * 16);
  for (int i = t; i < 320 * 4; i += 256) ((float4*)ABs)[i] = ABg[i];
  for (int i = t; i < 2560; i += 256) {
    int rl = i / 80, dq = i % 80;
    int n = min(n0 + rl, N_ - 1);
    size_t row = (size_t)bs_loc * N_ + n;
    float4 v;
    if (dq < 64) v = ((const float4*)z)[row * 64 + dq];
    else v = ((const float4*)xt)[((size_t)half * HROWS_ + row) * 16 + (dq - 64)];
    int d0 = dq * 4;
    Zs[rl][d0] = v.x; Zs[rl][d0 + 1] = v.y; Zs[rl][d0 + 2] = v.z; Zs[rl][d0 + 3] = v.w;
  }
  __syncthreads();
  float acc[4][4];
#pragma unroll
  for (int i = 0; i < 4; i++)
#pragma unroll
    for (int j = 0; j < 4; j++) acc[i][j] = 0.f;
  int rg = t & 7, tmp = t >> 3;
  int cg = tmp % 3, dc = tmp / 3;
  if (dc < 10) {
    int dbase = dc * 32;
    for (int dd = 0; dd < 32; dd++) {
      int d = dbase + dd;
      float4 ab = *(const float4*)&ABs[d][cg * 4];
      float a0 = Zs[rg * 4 + 0][d], a1 = Zs[rg * 4 + 1][d];
      float a2 = Zs[rg * 4 + 2][d], a3 = Zs[rg * 4 + 3][d];
      acc[0][0] += a0 * ab.x; acc[0][1] += a0 * ab.y; acc[0][2] += a0 * ab.z; acc[0][3] += a0 * ab.w;
      acc[1][0] += a1 * ab.x; acc[1][1] += a1 * ab.y; acc[1][2] += a1 * ab.z; acc[1][3] += a1 * ab.w;
      acc[2][0] += a2 * ab.x; acc[2][1] += a2 * ab.y; acc[2][2] += a2 * ab.z; acc[2][3] += a2 * ab.w;
      acc[3][0] += a3 * ab.x; acc[3][1] += a3 * ab.y; acc[3][2] += a3 * ab.z; acc[3][3] += a3 * ab.w;
    }
  }
  __syncthreads();
  float* red = &Zs[0][0];
  if (dc < 10) {
    int base = (((rg * 3 + cg) * 10) + dc) * 16;
#pragma unroll
    for (int i = 0; i < 4; i++)
      *(float4*)&red[base + i * 4] = make_float4(acc[i][0], acc[i][1], acc[i][2], acc[i][3]);
  }
  __syncthreads();
  for (int o = t; o < 384; o += 256) {
    int r = o / 12, co = o % 12;
    int rg2 = r >> 2, i2 = r & 3, cg2 = co >> 2, j2 = co & 3;
    float s0 = 0.f;
#pragma unroll
    for (int d2 = 0; d2 < 10; d2++)
      s0 += red[(((rg2 * 3 + cg2) * 10) + d2) * 16 + i2 * 4 + j2];
    int n = n0 + r;
    if (n < N_)
      partial[((size_t)half * HROWS_ + (size_t)bs_loc * N_ + n) * 12 + co] = s0;
  }
}

// ---------------- y = sum_s partial + cvec + 1{deg>0} dvec ----------------
__global__ void k_red(const float* __restrict__ partial, const float* __restrict__ cd,
                      const int* __restrict__ ptr, float* __restrict__ y) {
  int tg = blockIdx.x * 256 + threadIdx.x;
  if (tg >= B_ * N_ * 12) return;
  int bn = tg / 12, co = tg % 12;
  int b = bn / N_, n = bn % N_;
  float acc = cd[co];
  if (ptr[n + 1] > ptr[n]) acc += cd[16 + co];
  for (int s = 0; s < 12; s++)
    acc += partial[(((size_t)(b * 12 + s)) * N_ + n) * 12 + co];
  y[(size_t)bn * 12 + co] = acc;
}

extern "C" void kernel_launch(void* const* d_in, const int* in_sizes, int n_in,
                              void* d_out, int out_size, void* d_ws, size_t ws_size,
                              hipStream_t stream) {
  const float* x   = (const float*)d_in[0];
  const int*   ei  = (const int*)d_in[1];
  const float* Wg[4] = {(const float*)d_in[2], (const float*)d_in[4],
                        (const float*)d_in[6], (const float*)d_in[8]};
  const float* bg[4] = {(const float*)d_in[3], (const float*)d_in[5],
                        (const float*)d_in[7], (const float*)d_in[9]};
  const float* Wq = (const float*)d_in[10]; const float* bq = (const float*)d_in[11];
  const float* Wk = (const float*)d_in[12]; const float* bk = (const float*)d_in[13];
  const float* Wv = (const float*)d_in[14]; const float* bv = (const float*)d_in[15];
  const float* Ws = (const float*)d_in[16]; const float* bs = (const float*)d_in[17];
  const float* Wl = (const float*)d_in[18]; const float* bl = (const float*)d_in[19];
  float* y = (float*)d_out;

  char* p = (char*)d_ws;
  auto alloc = [&](size_t bytes) {
    char* r = p;
    p += (bytes + 255) & ~(size_t)255;
    return r;
  };
  float* dinv    = (float*)alloc(N_ * 4);
  int*   ptr_gcn = (int*)alloc((N_ + 1) * 4);
  int*   ptr_att = (int*)alloc((N_ + 1) * 4);
  int*   gcn_src = (int*)alloc(EN_ * 4);
  float* gcn_w   = (float*)alloc(EN_ * 4);
  int*   att_src = (int*)alloc(E_ * 4);
  float* AB      = (float*)alloc((size_t)12 * 320 * 16 * 4);  // 245 KB
  float* cd      = (float*)alloc(32 * 4);
  float* Wkt     = (float*)alloc((size_t)64 * QK_ * 4);       // 64 KB
  float* vc      = (float*)alloc(260 * 4);
  float* zero256 = (float*)alloc(256 * 4);
  float* bb      = (float*)alloc((size_t)ROWS_ * 4 * 4);      // 1 MB
  // ktb (64 MB, full rows) aliases [ag(16) | h0(16) | ktbext(32)] — ag/h0 dead
  // by the time the kt-GEMM runs (GCN finished, xt lives in h1).
  float* ag  = (float*)alloc((size_t)ROWS_ * H_ * 4);      // 16 MB
  float* h0  = (float*)alloc((size_t)ROWS_ * H_ * 4);      // 16 MB
  (void)     alloc((size_t)ROWS_ * QK_ * 4 - 2 * (size_t)ROWS_ * H_ * 4); // ktb ext
  float* ktb = ag;                                         // 64 MB full-row kt
  float* h1  = (float*)alloc((size_t)ROWS_ * H_ * 4);      // 16 MB (xt)
  float* zb  = (float*)alloc((size_t)HROWS_ * QK_ * 4);    // 32 MB (per half)
  float* partial = (float*)alloc((size_t)ROWS_ * 12 * 4);  // 3 MB
  (void)ws_size; (void)in_sizes; (void)n_in; (void)out_size;

  k_deg<<<1, 512, 0, stream>>>(ei, ptr_gcn, ptr_att, dinv);
  k_fill<<<(EN_ + 255) / 256, 256, 0, stream>>>(ei, ptr_gcn, ptr_att, dinv,
                                                gcn_src, gcn_w, att_src);
  k_abcd<<<306, 256, 0, stream>>>(Wv, Ws, Wl, bl, bs, bv, Wq, bq, Wk, bk,
                                  AB, cd, Wkt, vc, zero256);

  // GCN layers: agg (SpMM, XCD-partitioned) + tiled GEMM, ping-pong
  int agrid = 8 * 24 * NCH_;        // 15744
  int mt = (ROWS_ + 127) / 128;     // 488
  k_agg<CIN_><<<agrid, 256, 0, stream>>>(x, ptr_gcn, gcn_src, gcn_w, ag);
  k_gemm<CIN_, true><<<dim3(mt, 1), 256, 0, stream>>>(ag, ROWS_, Wg[0], bg[0], h0,
                                                      Wg[0], bg[0], h0, 64, 64, 1);
  k_agg<H_><<<agrid, 256, 0, stream>>>(h0, ptr_gcn, gcn_src, gcn_w, ag);
  k_gemm<H_, true><<<dim3(mt, 1), 256, 0, stream>>>(ag, ROWS_, Wg[1], bg[1], h1,
                                                    Wg[1], bg[1], h1, 64, 64, 1);
  k_agg<H_><<<agrid, 256, 0, stream>>>(h1, ptr_gcn, gcn_src, gcn_w, ag);
  k_gemm<H_, true><<<dim3(mt, 1), 256, 0, stream>>>(ag, ROWS_, Wg[2], bg[2], h0,
                                                    Wg[2], bg[2], h0, 64, 64, 1);
  k_agg<H_><<<agrid, 256, 0, stream>>>(h0, ptr_gcn, gcn_src, gcn_w, ag);
  k_gemm<H_, true><<<dim3(mt, 1), 256, 0, stream>>>(ag, ROWS_, Wg[3], bg[3], h1,
                                                    Wg[3], bg[3], h1, 64, 64, 1);

  // beta over all rows (depends only on xt = h1)
  k_beta<<<ROWS_ / 64, 256, 0, stream>>>(h1, vc, bb);

  // kt = xt @ Wkt over ALL rows in one launch (ktb aliases dead ag/h0)
  k_gemm<H_, false><<<dim3(mt, 4), 256, 0, stream>>>(h1, ROWS_, Wkt, zero256, ktb,
                                                     Wkt, zero256, ktb, QK_, QK_, 4);

  for (int half = 0; half < 2; half++) {
    k_attn4<<<HROWS_ / 4, 256, 0, stream>>>(ktb, h1, bb, ptr_att, att_src, half, zb);
    k_fin<<<dim3(HBS_, 11), 256, 0, stream>>>(zb, h1, AB, half, partial);
  }
  k_red<<<(B_ * N_ * 12 + 255) / 256, 256, 0, stream>>>(partial, cd, ptr_att, y);
}

// Round 17
// 390.527 us; speedup vs baseline: 1.0911x; 1.0156x over previous
//
#include <hip/hip_runtime.h>

#define B_ 16
#define S_ 12
#define N_ 325
#define E_ 2600
#define CIN_ 32
#define H_ 64
#define HEADS_ 4
#define COUT_ 12
#define BS_ (B_*S_)          // 192
#define ROWS_ (BS_*N_)       // 62400
#define EN_ (E_+N_)          // 2925
#define QK_ 256
#define HB_ (B_/2)           // 8 b per half
#define HBS_ (BS_/2)         // 96
#define HROWS_ (ROWS_/2)     // 31200
#define NCH_ 82              // ceil(N/4)

__device__ __forceinline__ int swz8(int bid, int cpx) {
  return (bid & 7) * cpx + (bid >> 3);   // grid must be multiple of 8
}

// ---------------- degree / norm / CSR pointers ----------------
__global__ void k_deg(const int* __restrict__ ei, int* __restrict__ ptr_gcn,
                      int* __restrict__ ptr_att, float* __restrict__ dinv) {
  __shared__ int cnt[N_];
  for (int i = threadIdx.x; i < N_; i += blockDim.x) cnt[i] = 0;
  __syncthreads();
  for (int e = threadIdx.x; e < E_; e += blockDim.x)
    atomicAdd(&cnt[ei[E_ + e]], 1);   // col = target
  __syncthreads();
  for (int n = threadIdx.x; n < N_; n += blockDim.x)
    dinv[n] = rsqrtf((float)(cnt[n] + 1));
  if (threadIdx.x == 0) {
    int a = 0, g = 0;
    for (int n = 0; n < N_; n++) {
      ptr_att[n] = a; ptr_gcn[n] = g;
      a += cnt[n]; g += cnt[n] + 1;   // gcn bucket has +1 self-loop slot
    }
    ptr_att[N_] = a; ptr_gcn[N_] = g;
  }
}

// ---------------- deterministic CSR fill (stable rank) ----------------
__global__ void k_fill(const int* __restrict__ ei, const int* __restrict__ ptr_gcn,
                       const int* __restrict__ ptr_att, const float* __restrict__ dinv,
                       int* __restrict__ gcn_src, float* __restrict__ gcn_w,
                       int* __restrict__ att_src) {
  __shared__ int cols[E_];
  for (int i = threadIdx.x; i < E_; i += blockDim.x) cols[i] = ei[E_ + i];
  __syncthreads();
  int e = blockIdx.x * blockDim.x + threadIdx.x;
  if (e >= EN_) return;
  int t = (e < E_) ? cols[e] : (e - E_);
  int s = (e < E_) ? ei[e]   : (e - E_);
  int lim = (e < E_) ? e : E_;
  int rank = 0;
  for (int j = 0; j < lim; j++) rank += (cols[j] == t);
  int pos = ptr_gcn[t] + rank;
  gcn_src[pos] = s;
  gcn_w[pos] = dinv[s] * dinv[t];
  if (e < E_) att_src[ptr_att[t] + rank] = s;
}

// ---------------- setup: AB, cd, Wkt (=G_h^T packed), vvec, c4, zero256 ----------------
__global__ void k_abcd(const float* __restrict__ Wv, const float* __restrict__ Wsm,
                       const float* __restrict__ Wl, const float* __restrict__ bl,
                       const float* __restrict__ bsv, const float* __restrict__ bvv,
                       const float* __restrict__ Wq, const float* __restrict__ bq,
                       const float* __restrict__ Wk, const float* __restrict__ bk,
                       float* __restrict__ AB, float* __restrict__ cd,
                       float* __restrict__ Wkt, float* __restrict__ vc,
                       float* __restrict__ zero256) {
  int t = threadIdx.x;
  if (blockIdx.x < 240) {
    int s = blockIdx.x / 20, dblk = blockIdx.x % 20;
    int dl = t >> 4, co = t & 15;
    int d = dblk * 16 + dl;             // 0..319
    float acc = 0.f;
    if (co < 12) {
      if (d < 256) {
        int h = d >> 6, dd = d & 63;
        for (int j = 0; j < 64; j++)
          acc += Wv[dd * 256 + h * 64 + j] * Wl[(size_t)(s * 256 + h * 64 + j) * 12 + co];
      } else {
        int d0 = d - 256;
        for (int J = 0; J < 256; J++)
          acc += Wsm[d0 * 256 + J] * Wl[(size_t)(s * 256 + J) * 12 + co];
      }
    }
    AB[((size_t)s * 320 + d) * 16 + co] = acc;
  } else if (blockIdx.x == 240) {
    __shared__ float red[2][16][17];
    int co = t & 15, chunk = t >> 4;
    float c = 0.f, dv = 0.f;
    if (co < 12) {
      for (int J = chunk * 192; J < chunk * 192 + 192; J++) {
        float wl = Wl[(size_t)J * 12 + co];
        c  += bsv[J & 255] * wl;
        dv += bvv[J & 255] * wl;
      }
    }
    red[0][chunk][co] = c;
    red[1][chunk][co] = dv;
    __syncthreads();
    if (t < 16) {
      float s0 = 0.f;
      for (int ch = 0; ch < 16; ch++) s0 += red[0][ch][t];
      cd[t] = s0 + ((t < 12) ? bl[t] : 0.f);
    } else if (t < 32) {
      int co2 = t - 16;
      float s1 = 0.f;
      for (int ch = 0; ch < 16; ch++) s1 += red[1][ch][co2];
      cd[16 + co2] = s1;
    }
  } else if (blockIdx.x < 305) {
    // Wkt[e][h*64+d] = G_h[d][e] = sum_i Wq[d][h*64+i] * Wk[e][h*64+i]
    int idx = (blockIdx.x - 241) * 256 + t;    // 0..16383
    int e = idx >> 8, col = idx & 255;
    int h = col >> 6, d = col & 63;
    float acc = 0.f;
    const float* wqr = Wq + (size_t)d * QK_ + h * 64;
    const float* wkr = Wk + (size_t)e * QK_ + h * 64;
#pragma unroll 8
    for (int i = 0; i < 64; i++) acc += wqr[i] * wkr[i];
    Wkt[(size_t)e * QK_ + col] = acc;
  } else {
    // vvec[h*64+e] = sum_i Wk[e][h*64+i] * bq[h*64+i] ; vc[256..259] = c_h ; zero256
    int h = t >> 6, e = t & 63;
    float acc = 0.f;
    const float* wkr = Wk + (size_t)e * QK_ + h * 64;
    const float* bqr = bq + h * 64;
#pragma unroll 8
    for (int i = 0; i < 64; i++) acc += wkr[i] * bqr[i];
    vc[t] = acc;
    if (t < 4) {
      float cc = 0.f;
      for (int i = 0; i < 64; i++) cc += bq[t * 64 + i] * bk[t * 64 + i];
      vc[256 + t] = cc;
    }
    zero256[t] = 0.f;
  }
}

// ---------------- GCN aggregation (SpMM), XCD-partitioned ----------------
template<int K>
__global__ __launch_bounds__(256) void k_agg(const float* __restrict__ hin,
    const int* __restrict__ ptr, const int* __restrict__ src,
    const float* __restrict__ wgt, float* __restrict__ ag) {
  int wid = threadIdx.x >> 6, lane = threadIdx.x & 63;
  int bid = blockIdx.x;                  // 15744 = 8 * 1968, 1968 = 24 * 82
  int xcd = bid & 7, sub = bid >> 3;
  int bs = xcd * 24 + sub / NCH_;        // contiguous per XCD
  int n = (sub % NCH_) * 4 + wid;
  if (n >= N_ || (K != 64 && lane >= K)) return;
  int p0 = ptr[n], p1 = ptr[n + 1];
  const float* base = hin + (size_t)bs * N_ * K;
  float a0 = 0.f, a1 = 0.f, a2 = 0.f, a3 = 0.f;
  int e = p0;
  for (; e + 4 <= p1; e += 4) {
    a0 += wgt[e]     * base[src[e]     * K + lane];
    a1 += wgt[e + 1] * base[src[e + 1] * K + lane];
    a2 += wgt[e + 2] * base[src[e + 2] * K + lane];
    a3 += wgt[e + 3] * base[src[e + 3] * K + lane];
  }
  for (; e < p1; ++e) a0 += wgt[e] * base[src[e] * K + lane];
  ag[((size_t)bs * N_ + n) * K + lane] = (a0 + a1) + (a2 + a3);
}

// ---------------- tiled GEMM, BM=64: C[64 x 64-slice] = A @ W + bias ----------------
// 975(x nct) blocks -> ~4 blocks/CU (36KB LDS), 4x4 micro-tile.
// BETA: epilogue also writes bb[row][ct] = A_row . vc[ct*64..] + vc[256+ct].
template<int K, bool RELU, bool BETA>
__global__ __launch_bounds__(256) void k_gemm(
    const float* __restrict__ A, int M,
    const float* __restrict__ W0, const float* __restrict__ b0, float* __restrict__ C0,
    const float* __restrict__ W1, const float* __restrict__ b1, float* __restrict__ C1,
    int wstride, int cstride, int nct,
    const float* __restrict__ vcp, float* __restrict__ bbout) {
  __shared__ float Ast[K][72];
  __shared__ float Wsh[K][68];
  int t = threadIdx.x;
  int ct = blockIdx.y;
  const float* W   = (ct < nct) ? W0 : W1;
  const float* bia = (ct < nct) ? b0 : b1;
  float* C         = (ct < nct) ? C0 : C1;
  int c0 = (ct & (nct - 1)) * 64;          // nct is 1 or 4 (power of 2)
  for (int i = t; i < K * 64; i += 256)
    Wsh[i >> 6][i & 63] = W[(size_t)(i >> 6) * wstride + c0 + (i & 63)];
  int r0 = blockIdx.x * 64;
#pragma unroll
  for (int it = 0; it < K / 16; ++it) {    // 64*(K/4)/256 iters
    int idx = it * 256 + t;
    int dq = idx >> 6, rl = idx & 63;
    int ar = min(r0 + rl, M - 1);
    float4 v = *(const float4*)(A + (size_t)ar * K + dq * 4);
    Ast[dq * 4 + 0][rl] = v.x; Ast[dq * 4 + 1][rl] = v.y;
    Ast[dq * 4 + 2][rl] = v.z; Ast[dq * 4 + 3][rl] = v.w;
  }
  __syncthreads();
  int tr = t >> 4, tc = t & 15;            // rows tr*4..+3, cols tc*4..+3
  float acc[4][4];
#pragma unroll
  for (int i = 0; i < 4; i++)
#pragma unroll
    for (int j = 0; j < 4; j++) acc[i][j] = 0.f;
#pragma unroll 8
  for (int k = 0; k < K; k++) {
    float4 w4 = *(const float4*)&Wsh[k][tc * 4];
    float4 a4 = *(const float4*)&Ast[k][tr * 4];
    const float av[4] = {a4.x, a4.y, a4.z, a4.w};
#pragma unroll
    for (int i = 0; i < 4; i++) {
      acc[i][0] += av[i] * w4.x; acc[i][1] += av[i] * w4.y;
      acc[i][2] += av[i] * w4.z; acc[i][3] += av[i] * w4.w;
    }
  }
  float4 b4 = *(const float4*)&bia[c0 + tc * 4];
#pragma unroll
  for (int i = 0; i < 4; i++) {
    int row = r0 + tr * 4 + i;
    if (row < M) {
      float4 o = make_float4(acc[i][0] + b4.x, acc[i][1] + b4.y,
                             acc[i][2] + b4.z, acc[i][3] + b4.w);
      if (RELU) {
        o.x = fmaxf(o.x, 0.f); o.y = fmaxf(o.y, 0.f);
        o.z = fmaxf(o.z, 0.f); o.w = fmaxf(o.w, 0.f);
      }
      *(float4*)(C + (size_t)row * cstride + c0 + tc * 4) = o;
    }
  }
  if (BETA) {
    // bb[row][ct] from the already-staged A tile (threads 0..63, conflict-free)
    if (t < 64) {
      int row = r0 + t;
      if (row < M) {
        float acc2 = vcp[256 + ct];
#pragma unroll 8
        for (int k = 0; k < K; k++) acc2 += Ast[k][t] * vcp[ct * 64 + k];
        bbout[(size_t)row * 4 + ct] = acc2;
      }
    }
  }
}

// ---------------- fused multi-head attention (R12 body + LDS w-broadcast PV) ----------------
__global__ void k_attn4(const float* __restrict__ kt, const float* __restrict__ xt,
                        const float* __restrict__ bb, const int* __restrict__ ptr,
                        const int* __restrict__ src, int half,
                        float* __restrict__ z) {
  __shared__ float xs[4][68];
  __shared__ float wbuf[4][64];
  int bid = swz8(blockIdx.x, 975);             // 7800/8
  int wid = threadIdx.x >> 6, lane = threadIdx.x & 63;
  int g = bid * 4 + wid;
  int n = g % N_, bsl = g / N_;
  int p0 = ptr[n], p1 = ptr[n + 1];
  const float* xb = xt + ((size_t)half * HBS_ + bsl) * N_ * 64;
  xs[wid][lane] = xb[(size_t)n * 64 + lane];   // same-wave write->read, no barrier
  int h = lane & 3, el = lane >> 2;
  const float* kb = kt + ((size_t)half * HBS_ + bsl) * N_ * QK_;
  const float* bbb = bb + ((size_t)half * HROWS_ + (size_t)bsl * N_) * 4;
  const float4* x4 = reinterpret_cast<const float4*>(&xs[wid][0]);
  float m = -INFINITY, den = 0.f;
  float zacc[4] = {0.f, 0.f, 0.f, 0.f};
  for (int base = p0; base < p1; base += 16) {
    int slot = base + el;
    bool valid = slot < p1;
    int sidx = valid ? src[slot] : 0;
    float logit = -INFINITY;
    if (valid) {
      const float4* k4 = reinterpret_cast<const float4*>(kb + (size_t)sidx * QK_ + h * 64);
      float d0 = 0.f, d1 = 0.f;
#pragma unroll
      for (int j = 0; j < 16; j += 2) {
        float4 ka = k4[j], kb2 = k4[j + 1];
        float4 xa = x4[j], xb2 = x4[j + 1];
        d0 += xa.x * ka.x + xa.y * ka.y + xa.z * ka.z + xa.w * ka.w;
        d1 += xb2.x * kb2.x + xb2.y * kb2.y + xb2.z * kb2.z + xb2.w * kb2.w;
      }
      logit = (d0 + d1 + bbb[sidx * 4 + h]) * 0.125f;   // 1/sqrt(64)
    }
    float cm = logit;
#pragma unroll
    for (int o = 4; o < 64; o <<= 1) cm = fmaxf(cm, __shfl_xor(cm, o));
    float mnew = fmaxf(m, cm);
    float scale = __expf(m - mnew);            // first chunk: exp(-inf)=0
    float w = valid ? __expf(logit - mnew) : 0.f;
    float wsum = w;
#pragma unroll
    for (int o = 4; o < 64; o <<= 1) wsum += __shfl_xor(wsum, o);
    den = den * scale + wsum;
    wbuf[wid][lane] = w;                       // same-wave DS order: visible below
#pragma unroll
    for (int h2 = 0; h2 < 4; h2++) zacc[h2] *= __shfl(scale, h2);
    int cnt = min(16, p1 - base);
    for (int e2 = 0; e2 < cnt; e2++) {
      int s_e = __shfl(sidx, e2 * 4);
      float xv = xb[(size_t)s_e * 64 + lane];
      float4 w4 = *(const float4*)&wbuf[wid][e2 * 4];  // broadcast, conflict-free
      zacc[0] += w4.x * xv; zacc[1] += w4.y * xv;
      zacc[2] += w4.z * xv; zacc[3] += w4.w * xv;
    }
    m = mnew;
  }
  bool ok = p1 > p0;
#pragma unroll
  for (int h2 = 0; h2 < 4; h2++) {
    float dh = __shfl(den, h2);
    z[(size_t)g * QK_ + h2 * 64 + lane] = ok ? zacc[h2] / (dh + 1e-16f) : 0.f;
  }
}

// ---------------- thin GEMM: partial[row][co] = [z|xt]_row(320) @ AB_s(320x12) ----------------
__global__ __launch_bounds__(256) void k_fin(const float* __restrict__ z,
    const float* __restrict__ xt, const float* __restrict__ AB, int half,
    float* __restrict__ partial) {
  __shared__ float Zs[32][327];
  __shared__ float ABs[320][16];
  int t = threadIdx.x;
  int bs_loc = blockIdx.x;           // 0..95
  int s = bs_loc % 12;
  int n0 = blockIdx.y * 32;
  const float4* ABg = (const float4*)(AB + (size_t)s * 320 * 16);
  for (int i = t; i < 320 * 4; i += 256) ((float4*)ABs)[i] = ABg[i];
  for (int i = t; i < 2560; i += 256) {
    int rl = i / 80, dq = i % 80;
    int n = min(n0 + rl, N_ - 1);
    size_t row = (size_t)bs_loc * N_ + n;
    float4 v;
    if (dq < 64) v = ((const float4*)z)[row * 64 + dq];
    else v = ((const float4*)xt)[((size_t)half * HROWS_ + row) * 16 + (dq - 64)];
    int d0 = dq * 4;
    Zs[rl][d0] = v.x; Zs[rl][d0 + 1] = v.y; Zs[rl][d0 + 2] = v.z; Zs[rl][d0 + 3] = v.w;
  }
  __syncthreads();
  float acc[4][4];
#pragma unroll
  for (int i = 0; i < 4; i++)
#pragma unroll
    for (int j = 0; j < 4; j++) acc[i][j] = 0.f;
  int rg = t & 7, tmp = t >> 3;
  int cg = tmp % 3, dc = tmp / 3;
  if (dc < 10) {
    int dbase = dc * 32;
    for (int dd = 0; dd < 32; dd++) {
      int d = dbase + dd;
      float4 ab = *(const float4*)&ABs[d][cg * 4];
      float a0 = Zs[rg * 4 + 0][d], a1 = Zs[rg * 4 + 1][d];
      float a2 = Zs[rg * 4 + 2][d], a3 = Zs[rg * 4 + 3][d];
      acc[0][0] += a0 * ab.x; acc[0][1] += a0 * ab.y; acc[0][2] += a0 * ab.z; acc[0][3] += a0 * ab.w;
      acc[1][0] += a1 * ab.x; acc[1][1] += a1 * ab.y; acc[1][2] += a1 * ab.z; acc[1][3] += a1 * ab.w;
      acc[2][0] += a2 * ab.x; acc[2][1] += a2 * ab.y; acc[2][2] += a2 * ab.z; acc[2][3] += a2 * ab.w;
      acc[3][0] += a3 * ab.x; acc[3][1] += a3 * ab.y; acc[3][2] += a3 * ab.z; acc[3][3] += a3 * ab.w;
    }
  }
  __syncthreads();
  float* red = &Zs[0][0];
  if (dc < 10) {
    int base = (((rg * 3 + cg) * 10) + dc) * 16;
#pragma unroll
    for (int i = 0; i < 4; i++)
      *(float4*)&red[base + i * 4] = make_float4(acc[i][0], acc[i][1], acc[i][2], acc[i][3]);
  }
  __syncthreads();
  for (int o = t; o < 384; o += 256) {
    int r = o / 12, co = o % 12;
    int rg2 = r >> 2, i2 = r & 3, cg2 = co >> 2, j2 = co & 3;
    float s0 = 0.f;
#pragma unroll
    for (int d2 = 0; d2 < 10; d2++)
      s0 += red[(((rg2 * 3 + cg2) * 10) + d2) * 16 + i2 * 4 + j2];
    int n = n0 + r;
    if (n < N_)
      partial[((size_t)half * HROWS_ + (size_t)bs_loc * N_ + n) * 12 + co] = s0;
  }
}

// ---------------- y = sum_s partial + cvec + 1{deg>0} dvec ----------------
__global__ void k_red(const float* __restrict__ partial, const float* __restrict__ cd,
                      const int* __restrict__ ptr, float* __restrict__ y) {
  int tg = blockIdx.x * 256 + threadIdx.x;
  if (tg >= B_ * N_ * 12) return;
  int bn = tg / 12, co = tg % 12;
  int b = bn / N_, n = bn % N_;
  float acc = cd[co];
  if (ptr[n + 1] > ptr[n]) acc += cd[16 + co];
  for (int s = 0; s < 12; s++)
    acc += partial[(((size_t)(b * 12 + s)) * N_ + n) * 12 + co];
  y[(size_t)bn * 12 + co] = acc;
}

extern "C" void kernel_launch(void* const* d_in, const int* in_sizes, int n_in,
                              void* d_out, int out_size, void* d_ws, size_t ws_size,
                              hipStream_t stream) {
  const float* x   = (const float*)d_in[0];
  const int*   ei  = (const int*)d_in[1];
  const float* Wg[4] = {(const float*)d_in[2], (const float*)d_in[4],
                        (const float*)d_in[6], (const float*)d_in[8]};
  const float* bg[4] = {(const float*)d_in[3], (const float*)d_in[5],
                        (const float*)d_in[7], (const float*)d_in[9]};
  const float* Wq = (const float*)d_in[10]; const float* bq = (const float*)d_in[11];
  const float* Wk = (const float*)d_in[12]; const float* bk = (const float*)d_in[13];
  const float* Wv = (const float*)d_in[14]; const float* bv = (const float*)d_in[15];
  const float* Ws = (const float*)d_in[16]; const float* bs = (const float*)d_in[17];
  const float* Wl = (const float*)d_in[18]; const float* bl = (const float*)d_in[19];
  float* y = (float*)d_out;

  char* p = (char*)d_ws;
  auto alloc = [&](size_t bytes) {
    char* r = p;
    p += (bytes + 255) & ~(size_t)255;
    return r;
  };
  float* dinv    = (float*)alloc(N_ * 4);
  int*   ptr_gcn = (int*)alloc((N_ + 1) * 4);
  int*   ptr_att = (int*)alloc((N_ + 1) * 4);
  int*   gcn_src = (int*)alloc(EN_ * 4);
  float* gcn_w   = (float*)alloc(EN_ * 4);
  int*   att_src = (int*)alloc(E_ * 4);
  float* AB      = (float*)alloc((size_t)12 * 320 * 16 * 4);  // 245 KB
  float* cd      = (float*)alloc(32 * 4);
  float* Wkt     = (float*)alloc((size_t)64 * QK_ * 4);       // 64 KB
  float* vc      = (float*)alloc(260 * 4);
  float* zero256 = (float*)alloc(256 * 4);
  float* bb      = (float*)alloc((size_t)ROWS_ * 4 * 4);      // 1 MB
  // ktb (64 MB, full rows) aliases [ag(16) | h0(16) | ktbext(32)] — ag/h0 dead
  // by the time the kt-GEMM runs (GCN finished, xt lives in h1).
  float* ag  = (float*)alloc((size_t)ROWS_ * H_ * 4);      // 16 MB
  float* h0  = (float*)alloc((size_t)ROWS_ * H_ * 4);      // 16 MB
  (void)     alloc((size_t)ROWS_ * QK_ * 4 - 2 * (size_t)ROWS_ * H_ * 4); // ktb ext
  float* ktb = ag;                                         // 64 MB full-row kt
  float* h1  = (float*)alloc((size_t)ROWS_ * H_ * 4);      // 16 MB (xt)
  float* zb  = (float*)alloc((size_t)HROWS_ * QK_ * 4);    // 32 MB (per half)
  float* partial = (float*)alloc((size_t)ROWS_ * 12 * 4);  // 3 MB
  (void)ws_size; (void)in_sizes; (void)n_in; (void)out_size;

  k_deg<<<1, 512, 0, stream>>>(ei, ptr_gcn, ptr_att, dinv);
  k_fill<<<(EN_ + 255) / 256, 256, 0, stream>>>(ei, ptr_gcn, ptr_att, dinv,
                                                gcn_src, gcn_w, att_src);
  k_abcd<<<306, 256, 0, stream>>>(Wv, Ws, Wl, bl, bs, bv, Wq, bq, Wk, bk,
                                  AB, cd, Wkt, vc, zero256);

  // GCN layers: agg (SpMM, XCD-partitioned) + tiled GEMM (BM=64), ping-pong
  int agrid = 8 * 24 * NCH_;        // 15744
  int mt = ROWS_ / 64;              // 975 exact
  k_agg<CIN_><<<agrid, 256, 0, stream>>>(x, ptr_gcn, gcn_src, gcn_w, ag);
  k_gemm<CIN_, true, false><<<dim3(mt, 1), 256, 0, stream>>>(
      ag, ROWS_, Wg[0], bg[0], h0, Wg[0], bg[0], h0, 64, 64, 1, nullptr, nullptr);
  k_agg<H_><<<agrid, 256, 0, stream>>>(h0, ptr_gcn, gcn_src, gcn_w, ag);
  k_gemm<H_, true, false><<<dim3(mt, 1), 256, 0, stream>>>(
      ag, ROWS_, Wg[1], bg[1], h1, Wg[1], bg[1], h1, 64, 64, 1, nullptr, nullptr);
  k_agg<H_><<<agrid, 256, 0, stream>>>(h1, ptr_gcn, gcn_src, gcn_w, ag);
  k_gemm<H_, true, false><<<dim3(mt, 1), 256, 0, stream>>>(
      ag, ROWS_, Wg[2], bg[2], h0, Wg[2], bg[2], h0, 64, 64, 1, nullptr, nullptr);
  k_agg<H_><<<agrid, 256, 0, stream>>>(h0, ptr_gcn, gcn_src, gcn_w, ag);
  k_gemm<H_, true, false><<<dim3(mt, 1), 256, 0, stream>>>(
      ag, ROWS_, Wg[3], bg[3], h1, Wg[3], bg[3], h1, 64, 64, 1, nullptr, nullptr);

  // kt = xt @ Wkt over ALL rows, one launch; beta fused into epilogue
  k_gemm<H_, false, true><<<dim3(mt, 4), 256, 0, stream>>>(
      h1, ROWS_, Wkt, zero256, ktb, Wkt, zero256, ktb, QK_, QK_, 4, vc, bb);

  for (int half = 0; half < 2; half++) {
    k_attn4<<<HROWS_ / 4, 256, 0, stream>>>(ktb, h1, bb, ptr_att, att_src, half, zb);
    k_fin<<<dim3(HBS_, 11), 256, 0, stream>>>(zb, h1, AB, half, partial);
  }
  k_red<<<(B_ * N_ * 12 + 255) / 256, 256, 0, stream>>>(partial, cd, ptr_att, y);
}

// Round 18
// 377.751 us; speedup vs baseline: 1.1280x; 1.0338x over previous
//
#include <hip/hip_runtime.h>
#include <hip/hip_fp16.h>

#define B_ 16
#define S_ 12
#define N_ 325
#define E_ 2600
#define CIN_ 32
#define H_ 64
#define HEADS_ 4
#define COUT_ 12
#define BS_ (B_*S_)          // 192
#define ROWS_ (BS_*N_)       // 62400 = 8 * 7800
#define EN_ (E_+N_)          // 2925
#define QK_ 256
#define NCH_ 82              // ceil(N/4)
#define RPX_ 7800            // rows per XCD region (24 bs)

// ---------------- degree / norm / CSR pointers ----------------
__global__ void k_deg(const int* __restrict__ ei, int* __restrict__ ptr_gcn,
                      int* __restrict__ ptr_att, float* __restrict__ dinv) {
  __shared__ int cnt[N_];
  for (int i = threadIdx.x; i < N_; i += blockDim.x) cnt[i] = 0;
  __syncthreads();
  for (int e = threadIdx.x; e < E_; e += blockDim.x)
    atomicAdd(&cnt[ei[E_ + e]], 1);   // col = target
  __syncthreads();
  for (int n = threadIdx.x; n < N_; n += blockDim.x)
    dinv[n] = rsqrtf((float)(cnt[n] + 1));
  if (threadIdx.x == 0) {
    int a = 0, g = 0;
    for (int n = 0; n < N_; n++) {
      ptr_att[n] = a; ptr_gcn[n] = g;
      a += cnt[n]; g += cnt[n] + 1;   // gcn bucket has +1 self-loop slot
    }
    ptr_att[N_] = a; ptr_gcn[N_] = g;
  }
}

// ---------------- deterministic CSR fill (stable rank) ----------------
__global__ void k_fill(const int* __restrict__ ei, const int* __restrict__ ptr_gcn,
                       const int* __restrict__ ptr_att, const float* __restrict__ dinv,
                       int* __restrict__ gcn_src, float* __restrict__ gcn_w,
                       int* __restrict__ att_src) {
  __shared__ int cols[E_];
  for (int i = threadIdx.x; i < E_; i += blockDim.x) cols[i] = ei[E_ + i];
  __syncthreads();
  int e = blockIdx.x * blockDim.x + threadIdx.x;
  if (e >= EN_) return;
  int t = (e < E_) ? cols[e] : (e - E_);
  int s = (e < E_) ? ei[e]   : (e - E_);
  int lim = (e < E_) ? e : E_;
  int rank = 0;
  for (int j = 0; j < lim; j++) rank += (cols[j] == t);
  int pos = ptr_gcn[t] + rank;
  gcn_src[pos] = s;
  gcn_w[pos] = dinv[s] * dinv[t];
  if (e < E_) att_src[ptr_att[t] + rank] = s;
}

// ---------------- setup: AB, cd, Wkt (=G_h^T packed), vvec, c4, zero256 ----------------
__global__ void k_abcd(const float* __restrict__ Wv, const float* __restrict__ Wsm,
                       const float* __restrict__ Wl, const float* __restrict__ bl,
                       const float* __restrict__ bsv, const float* __restrict__ bvv,
                       const float* __restrict__ Wq, const float* __restrict__ bq,
                       const float* __restrict__ Wk, const float* __restrict__ bk,
                       float* __restrict__ AB, float* __restrict__ cd,
                       float* __restrict__ Wkt, float* __restrict__ vc,
                       float* __restrict__ zero256) {
  int t = threadIdx.x;
  if (blockIdx.x < 240) {
    int s = blockIdx.x / 20, dblk = blockIdx.x % 20;
    int dl = t >> 4, co = t & 15;
    int d = dblk * 16 + dl;             // 0..319
    float acc = 0.f;
    if (co < 12) {
      if (d < 256) {
        int h = d >> 6, dd = d & 63;
        for (int j = 0; j < 64; j++)
          acc += Wv[dd * 256 + h * 64 + j] * Wl[(size_t)(s * 256 + h * 64 + j) * 12 + co];
      } else {
        int d0 = d - 256;
        for (int J = 0; J < 256; J++)
          acc += Wsm[d0 * 256 + J] * Wl[(size_t)(s * 256 + J) * 12 + co];
      }
    }
    AB[((size_t)s * 320 + d) * 16 + co] = acc;
  } else if (blockIdx.x == 240) {
    __shared__ float red[2][16][17];
    int co = t & 15, chunk = t >> 4;
    float c = 0.f, dv = 0.f;
    if (co < 12) {
      for (int J = chunk * 192; J < chunk * 192 + 192; J++) {
        float wl = Wl[(size_t)J * 12 + co];
        c  += bsv[J & 255] * wl;
        dv += bvv[J & 255] * wl;
      }
    }
    red[0][chunk][co] = c;
    red[1][chunk][co] = dv;
    __syncthreads();
    if (t < 16) {
      float s0 = 0.f;
      for (int ch = 0; ch < 16; ch++) s0 += red[0][ch][t];
      cd[t] = s0 + ((t < 12) ? bl[t] : 0.f);
    } else if (t < 32) {
      int co2 = t - 16;
      float s1 = 0.f;
      for (int ch = 0; ch < 16; ch++) s1 += red[1][ch][co2];
      cd[16 + co2] = s1;
    }
  } else if (blockIdx.x < 305) {
    // Wkt[e][h*64+d] = G_h[d][e] = sum_i Wq[d][h*64+i] * Wk[e][h*64+i]
    int idx = (blockIdx.x - 241) * 256 + t;    // 0..16383
    int e = idx >> 8, col = idx & 255;
    int h = col >> 6, d = col & 63;
    float acc = 0.f;
    const float* wqr = Wq + (size_t)d * QK_ + h * 64;
    const float* wkr = Wk + (size_t)e * QK_ + h * 64;
#pragma unroll 8
    for (int i = 0; i < 64; i++) acc += wqr[i] * wkr[i];
    Wkt[(size_t)e * QK_ + col] = acc;
  } else {
    int h = t >> 6, e = t & 63;
    float acc = 0.f;
    const float* wkr = Wk + (size_t)e * QK_ + h * 64;
    const float* bqr = bq + h * 64;
#pragma unroll 8
    for (int i = 0; i < 64; i++) acc += wkr[i] * bqr[i];
    vc[t] = acc;
    if (t < 4) {
      float cc = 0.f;
      for (int i = 0; i < 64; i++) cc += bq[t * 64 + i] * bk[t * 64 + i];
      vc[256 + t] = cc;
    }
    zero256[t] = 0.f;
  }
}

// ---------------- GCN aggregation (SpMM), XCD-partitioned ----------------
template<int K>
__global__ __launch_bounds__(256) void k_agg(const float* __restrict__ hin,
    const int* __restrict__ ptr, const int* __restrict__ src,
    const float* __restrict__ wgt, float* __restrict__ ag) {
  int wid = threadIdx.x >> 6, lane = threadIdx.x & 63;
  int bid = blockIdx.x;                  // 15744 = 8 * 1968, 1968 = 24 * 82
  int xcd = bid & 7, sub = bid >> 3;
  int bs = xcd * 24 + sub / NCH_;        // contiguous per XCD
  int n = (sub % NCH_) * 4 + wid;
  if (n >= N_ || (K != 64 && lane >= K)) return;
  int p0 = ptr[n], p1 = ptr[n + 1];
  const float* base = hin + (size_t)bs * N_ * K;
  float a0 = 0.f, a1 = 0.f, a2 = 0.f, a3 = 0.f;
  int e = p0;
  for (; e + 4 <= p1; e += 4) {
    a0 += wgt[e]     * base[src[e]     * K + lane];
    a1 += wgt[e + 1] * base[src[e + 1] * K + lane];
    a2 += wgt[e + 2] * base[src[e + 2] * K + lane];
    a3 += wgt[e + 3] * base[src[e + 3] * K + lane];
  }
  for (; e < p1; ++e) a0 += wgt[e] * base[src[e] * K + lane];
  ag[((size_t)bs * N_ + n) * K + lane] = (a0 + a1) + (a2 + a3);
}

// ---------------- tiled GEMM, BM=64, XCD-partitioned ----------------
// grid (976 = 8*122, nct): xcd = bid&7 owns rows [xcd*7800, +7800) exactly.
template<int K, bool RELU, bool BETA>
__global__ __launch_bounds__(256) void k_gemm(
    const float* __restrict__ A, int M,
    const float* __restrict__ W0, const float* __restrict__ b0, float* __restrict__ C0,
    const float* __restrict__ W1, const float* __restrict__ b1, float* __restrict__ C1,
    int wstride, int cstride, int nct,
    const float* __restrict__ vcp, float* __restrict__ bbout) {
  __shared__ float Ast[K][72];
  __shared__ float Wsh[K][68];
  int t = threadIdx.x;
  int ct = blockIdx.y;
  const float* W   = (ct < nct) ? W0 : W1;
  const float* bia = (ct < nct) ? b0 : b1;
  float* C         = (ct < nct) ? C0 : C1;
  int c0 = (ct & (nct - 1)) * 64;
  for (int i = t; i < K * 64; i += 256)
    Wsh[i >> 6][i & 63] = W[(size_t)(i >> 6) * wstride + c0 + (i & 63)];
  int bid = blockIdx.x;                    // 976 = 8 * 122
  int xcd = bid & 7, sub = bid >> 3;       // sub 0..121, sub*64 covers 7800 (+tail)
  int r0 = xcd * RPX_ + sub * 64;
#pragma unroll
  for (int it = 0; it < K / 16; ++it) {
    int idx = it * 256 + t;
    int dq = idx >> 6, rl = idx & 63;
    int ar = min(r0 + rl, M - 1);
    float4 v = *(const float4*)(A + (size_t)ar * K + dq * 4);
    Ast[dq * 4 + 0][rl] = v.x; Ast[dq * 4 + 1][rl] = v.y;
    Ast[dq * 4 + 2][rl] = v.z; Ast[dq * 4 + 3][rl] = v.w;
  }
  __syncthreads();
  int tr = t >> 4, tc = t & 15;
  float acc[4][4];
#pragma unroll
  for (int i = 0; i < 4; i++)
#pragma unroll
    for (int j = 0; j < 4; j++) acc[i][j] = 0.f;
#pragma unroll 8
  for (int k = 0; k < K; k++) {
    float4 w4 = *(const float4*)&Wsh[k][tc * 4];
    float4 a4 = *(const float4*)&Ast[k][tr * 4];
    const float av[4] = {a4.x, a4.y, a4.z, a4.w};
#pragma unroll
    for (int i = 0; i < 4; i++) {
      acc[i][0] += av[i] * w4.x; acc[i][1] += av[i] * w4.y;
      acc[i][2] += av[i] * w4.z; acc[i][3] += av[i] * w4.w;
    }
  }
  float4 b4 = *(const float4*)&bia[c0 + tc * 4];
#pragma unroll
  for (int i = 0; i < 4; i++) {
    int lrow = sub * 64 + tr * 4 + i;      // region-local guard (region = 7800)
    if (lrow < RPX_) {
      int row = r0 + tr * 4 + i;
      float4 o = make_float4(acc[i][0] + b4.x, acc[i][1] + b4.y,
                             acc[i][2] + b4.z, acc[i][3] + b4.w);
      if (RELU) {
        o.x = fmaxf(o.x, 0.f); o.y = fmaxf(o.y, 0.f);
        o.z = fmaxf(o.z, 0.f); o.w = fmaxf(o.w, 0.f);
      }
      *(float4*)(C + (size_t)row * cstride + c0 + tc * 4) = o;
    }
  }
  if (BETA) {
    if (t < 64) {
      int lrow = sub * 64 + t;
      if (lrow < RPX_) {
        int row = r0 + t;
        float acc2 = vcp[256 + ct];
#pragma unroll 8
        for (int k = 0; k < K; k++) acc2 += Ast[k][t] * vcp[ct * 64 + k];
        bbout[(size_t)row * 4 + ct] = acc2;
      }
    }
  }
}

// ---------------- fused multi-head attention, full-row, XCD-partitioned ----------------
// grid 15600 = 8 * 1950: xcd = bid&7 owns rows [xcd*7800, +7800) — kt/xt/bb local L2.
// z written as fp16 (halves traffic; err ~5e-4 << threshold).
__global__ void k_attn4(const float* __restrict__ kt, const float* __restrict__ xt,
                        const float* __restrict__ bb, const int* __restrict__ ptr,
                        const int* __restrict__ src, __half* __restrict__ zh) {
  __shared__ float xs[4][68];
  __shared__ float wbuf[4][64];
  int wid = threadIdx.x >> 6, lane = threadIdx.x & 63;
  int bid = blockIdx.x;                    // 15600 = 8 * 1950
  int xcd = bid & 7, sub = bid >> 3;
  int g = xcd * RPX_ + sub * 4 + wid;      // 1950*4 = 7800 exact
  int n = g % N_, gbs = g / N_;
  int p0 = ptr[n], p1 = ptr[n + 1];
  const float* xb = xt + (size_t)gbs * N_ * 64;
  xs[wid][lane] = xb[(size_t)n * 64 + lane];   // same-wave write->read
  int h = lane & 3, el = lane >> 2;
  const float* kb = kt + (size_t)gbs * N_ * QK_;
  const float* bbb = bb + (size_t)gbs * N_ * 4;
  const float4* x4 = reinterpret_cast<const float4*>(&xs[wid][0]);
  float m = -INFINITY, den = 0.f;
  float zacc[4] = {0.f, 0.f, 0.f, 0.f};
  for (int base = p0; base < p1; base += 16) {
    int slot = base + el;
    bool valid = slot < p1;
    int sidx = valid ? src[slot] : 0;
    float logit = -INFINITY;
    if (valid) {
      const float4* k4 = reinterpret_cast<const float4*>(kb + (size_t)sidx * QK_ + h * 64);
      float d0 = 0.f, d1 = 0.f;
#pragma unroll
      for (int j = 0; j < 16; j += 2) {
        float4 ka = k4[j], kb2 = k4[j + 1];
        float4 xa = x4[j], xb2 = x4[j + 1];
        d0 += xa.x * ka.x + xa.y * ka.y + xa.z * ka.z + xa.w * ka.w;
        d1 += xb2.x * kb2.x + xb2.y * kb2.y + xb2.z * kb2.z + xb2.w * kb2.w;
      }
      logit = (d0 + d1 + bbb[sidx * 4 + h]) * 0.125f;   // 1/sqrt(64)
    }
    float cm = logit;
#pragma unroll
    for (int o = 4; o < 64; o <<= 1) cm = fmaxf(cm, __shfl_xor(cm, o));
    float mnew = fmaxf(m, cm);
    float scale = __expf(m - mnew);        // first chunk: exp(-inf)=0
    float w = valid ? __expf(logit - mnew) : 0.f;
    float wsum = w;
#pragma unroll
    for (int o = 4; o < 64; o <<= 1) wsum += __shfl_xor(wsum, o);
    den = den * scale + wsum;
    wbuf[wid][lane] = w;                   // same-wave DS order
#pragma unroll
    for (int h2 = 0; h2 < 4; h2++) zacc[h2] *= __shfl(scale, h2);
    int cnt = min(16, p1 - base);
    for (int e2 = 0; e2 < cnt; e2++) {
      int s_e = __shfl(sidx, e2 * 4);
      float xv = xb[(size_t)s_e * 64 + lane];
      float4 w4 = *(const float4*)&wbuf[wid][e2 * 4];  // broadcast, conflict-free
      zacc[0] += w4.x * xv; zacc[1] += w4.y * xv;
      zacc[2] += w4.z * xv; zacc[3] += w4.w * xv;
    }
    m = mnew;
  }
  bool ok = p1 > p0;
#pragma unroll
  for (int h2 = 0; h2 < 4; h2++) {
    float dh = __shfl(den, h2);
    zh[(size_t)g * QK_ + h2 * 64 + lane] =
        __float2half(ok ? zacc[h2] / (dh + 1e-16f) : 0.f);
  }
}

// ---------------- thin GEMM, XCD-partitioned: partial = [z|xt](320) @ AB_s(320x12) ------
__global__ __launch_bounds__(256) void k_fin(const __half* __restrict__ zh,
    const float* __restrict__ xt, const float* __restrict__ AB,
    float* __restrict__ partial) {
  __shared__ float Zs[32][327];
  __shared__ float ABs[320][16];
  int t = threadIdx.x;
  int bid = blockIdx.x;              // 2112 = 8 * 264, 264 = 24 * 11
  int xcd = bid & 7, sub = bid >> 3;
  int bs = xcd * 24 + sub / 11;
  int n0 = (sub % 11) * 32;
  int s = bs % 12;
  const float4* ABg = (const float4*)(AB + (size_t)s * 320 * 16);
  for (int i = t; i < 320 * 4; i += 256) ((float4*)ABs)[i] = ABg[i];
  for (int i = t; i < 2560; i += 256) {
    int rl = i / 80, dq = i % 80;
    int n = min(n0 + rl, N_ - 1);
    size_t row = (size_t)bs * N_ + n;
    float4 v;
    if (dq < 64) {
      const __half2* zp = (const __half2*)(zh + row * QK_ + dq * 4);
      __half2 ha = zp[0], hb = zp[1];
      v = make_float4(__low2float(ha), __high2float(ha),
                      __low2float(hb), __high2float(hb));
    } else {
      v = ((const float4*)xt)[row * 16 + (dq - 64)];
    }
    int d0 = dq * 4;
    Zs[rl][d0] = v.x; Zs[rl][d0 + 1] = v.y; Zs[rl][d0 + 2] = v.z; Zs[rl][d0 + 3] = v.w;
  }
  __syncthreads();
  float acc[4][4];
#pragma unroll
  for (int i = 0; i < 4; i++)
#pragma unroll
    for (int j = 0; j < 4; j++) acc[i][j] = 0.f;
  int rg = t & 7, tmp = t >> 3;
  int cg = tmp % 3, dc = tmp / 3;
  if (dc < 10) {
    int dbase = dc * 32;
    for (int dd = 0; dd < 32; dd++) {
      int d = dbase + dd;
      float4 ab = *(const float4*)&ABs[d][cg * 4];
      float a0 = Zs[rg * 4 + 0][d], a1 = Zs[rg * 4 + 1][d];
      float a2 = Zs[rg * 4 + 2][d], a3 = Zs[rg * 4 + 3][d];
      acc[0][0] += a0 * ab.x; acc[0][1] += a0 * ab.y; acc[0][2] += a0 * ab.z; acc[0][3] += a0 * ab.w;
      acc[1][0] += a1 * ab.x; acc[1][1] += a1 * ab.y; acc[1][2] += a1 * ab.z; acc[1][3] += a1 * ab.w;
      acc[2][0] += a2 * ab.x; acc[2][1] += a2 * ab.y; acc[2][2] += a2 * ab.z; acc[2][3] += a2 * ab.w;
      acc[3][0] += a3 * ab.x; acc[3][1] += a3 * ab.y; acc[3][2] += a3 * ab.z; acc[3][3] += a3 * ab.w;
    }
  }
  __syncthreads();
  float* red = &Zs[0][0];
  if (dc < 10) {
    int base = (((rg * 3 + cg) * 10) + dc) * 16;
#pragma unroll
    for (int i = 0; i < 4; i++)
      *(float4*)&red[base + i * 4] = make_float4(acc[i][0], acc[i][1], acc[i][2], acc[i][3]);
  }
  __syncthreads();
  for (int o = t; o < 384; o += 256) {
    int r = o / 12, co = o % 12;
    int rg2 = r >> 2, i2 = r & 3, cg2 = co >> 2, j2 = co & 3;
    float s0 = 0.f;
#pragma unroll
    for (int d2 = 0; d2 < 10; d2++)
      s0 += red[(((rg2 * 3 + cg2) * 10) + d2) * 16 + i2 * 4 + j2];
    int n = n0 + r;
    if (n < N_)
      partial[((size_t)bs * N_ + n) * 12 + co] = s0;
  }
}

// ---------------- y = sum_s partial + cvec + 1{deg>0} dvec ----------------
__global__ void k_red(const float* __restrict__ partial, const float* __restrict__ cd,
                      const int* __restrict__ ptr, float* __restrict__ y) {
  int tg = blockIdx.x * 256 + threadIdx.x;
  if (tg >= B_ * N_ * 12) return;
  int bn = tg / 12, co = tg % 12;
  int b = bn / N_, n = bn % N_;
  float acc = cd[co];
  if (ptr[n + 1] > ptr[n]) acc += cd[16 + co];
  for (int s = 0; s < 12; s++)
    acc += partial[(((size_t)(b * 12 + s)) * N_ + n) * 12 + co];
  y[(size_t)bn * 12 + co] = acc;
}

extern "C" void kernel_launch(void* const* d_in, const int* in_sizes, int n_in,
                              void* d_out, int out_size, void* d_ws, size_t ws_size,
                              hipStream_t stream) {
  const float* x   = (const float*)d_in[0];
  const int*   ei  = (const int*)d_in[1];
  const float* Wg[4] = {(const float*)d_in[2], (const float*)d_in[4],
                        (const float*)d_in[6], (const float*)d_in[8]};
  const float* bg[4] = {(const float*)d_in[3], (const float*)d_in[5],
                        (const float*)d_in[7], (const float*)d_in[9]};
  const float* Wq = (const float*)d_in[10]; const float* bq = (const float*)d_in[11];
  const float* Wk = (const float*)d_in[12]; const float* bk = (const float*)d_in[13];
  const float* Wv = (const float*)d_in[14]; const float* bv = (const float*)d_in[15];
  const float* Ws = (const float*)d_in[16]; const float* bs = (const float*)d_in[17];
  const float* Wl = (const float*)d_in[18]; const float* bl = (const float*)d_in[19];
  float* y = (float*)d_out;

  char* p = (char*)d_ws;
  auto alloc = [&](size_t bytes) {
    char* r = p;
    p += (bytes + 255) & ~(size_t)255;
    return r;
  };
  float* dinv    = (float*)alloc(N_ * 4);
  int*   ptr_gcn = (int*)alloc((N_ + 1) * 4);
  int*   ptr_att = (int*)alloc((N_ + 1) * 4);
  int*   gcn_src = (int*)alloc(EN_ * 4);
  float* gcn_w   = (float*)alloc(EN_ * 4);
  int*   att_src = (int*)alloc(E_ * 4);
  float* AB      = (float*)alloc((size_t)12 * 320 * 16 * 4);  // 245 KB
  float* cd      = (float*)alloc(32 * 4);
  float* Wkt     = (float*)alloc((size_t)64 * QK_ * 4);       // 64 KB
  float* vc      = (float*)alloc(260 * 4);
  float* zero256 = (float*)alloc(256 * 4);
  float* bb      = (float*)alloc((size_t)ROWS_ * 4 * 4);      // 1 MB
  // ktb (64 MB full-row) aliases [ag | h0 | ext] — ag/h0 dead after GCN.
  float* ag  = (float*)alloc((size_t)ROWS_ * H_ * 4);      // 16 MB
  float* h0  = (float*)alloc((size_t)ROWS_ * H_ * 4);      // 16 MB
  (void)     alloc((size_t)ROWS_ * QK_ * 4 - 2 * (size_t)ROWS_ * H_ * 4);
  float* ktb = ag;                                         // 64 MB full-row kt
  float* h1  = (float*)alloc((size_t)ROWS_ * H_ * 4);      // 16 MB (xt)
  __half* zh = (__half*)alloc((size_t)ROWS_ * QK_ * 2);    // 32 MB (fp16 z, full-row)
  float* partial = (float*)alloc((size_t)ROWS_ * 12 * 4);  // 3 MB
  (void)ws_size; (void)in_sizes; (void)n_in; (void)out_size;

  k_deg<<<1, 512, 0, stream>>>(ei, ptr_gcn, ptr_att, dinv);
  k_fill<<<(EN_ + 255) / 256, 256, 0, stream>>>(ei, ptr_gcn, ptr_att, dinv,
                                                gcn_src, gcn_w, att_src);
  k_abcd<<<306, 256, 0, stream>>>(Wv, Ws, Wl, bl, bs, bv, Wq, bq, Wk, bk,
                                  AB, cd, Wkt, vc, zero256);

  // GCN layers: agg (SpMM) + tiled GEMM, both XCD-partitioned, ping-pong
  int agrid = 8 * 24 * NCH_;        // 15744
  int ggrid = 8 * 122;              // 976 (122*64 covers 7800-row region)
  k_agg<CIN_><<<agrid, 256, 0, stream>>>(x, ptr_gcn, gcn_src, gcn_w, ag);
  k_gemm<CIN_, true, false><<<dim3(ggrid, 1), 256, 0, stream>>>(
      ag, ROWS_, Wg[0], bg[0], h0, Wg[0], bg[0], h0, 64, 64, 1, nullptr, nullptr);
  k_agg<H_><<<agrid, 256, 0, stream>>>(h0, ptr_gcn, gcn_src, gcn_w, ag);
  k_gemm<H_, true, false><<<dim3(ggrid, 1), 256, 0, stream>>>(
      ag, ROWS_, Wg[1], bg[1], h1, Wg[1], bg[1], h1, 64, 64, 1, nullptr, nullptr);
  k_agg<H_><<<agrid, 256, 0, stream>>>(h1, ptr_gcn, gcn_src, gcn_w, ag);
  k_gemm<H_, true, false><<<dim3(ggrid, 1), 256, 0, stream>>>(
      ag, ROWS_, Wg[2], bg[2], h0, Wg[2], bg[2], h0, 64, 64, 1, nullptr, nullptr);
  k_agg<H_><<<agrid, 256, 0, stream>>>(h0, ptr_gcn, gcn_src, gcn_w, ag);
  k_gemm<H_, true, false><<<dim3(ggrid, 1), 256, 0, stream>>>(
      ag, ROWS_, Wg[3], bg[3], h1, Wg[3], bg[3], h1, 64, 64, 1, nullptr, nullptr);

  // kt = xt @ Wkt over ALL rows; beta fused into epilogue
  k_gemm<H_, false, true><<<dim3(ggrid, 4), 256, 0, stream>>>(
      h1, ROWS_, Wkt, zero256, ktb, Wkt, zero256, ktb, QK_, QK_, 4, vc, bb);

  // attention + fin, single full-row XCD-aligned launches
  k_attn4<<<8 * (RPX_ / 4), 256, 0, stream>>>(ktb, h1, bb, ptr_att, att_src, zh);
  k_fin<<<8 * 24 * 11, 256, 0, stream>>>(zh, h1, AB, partial);

  k_red<<<(B_ * N_ * 12 + 255) / 256, 256, 0, stream>>>(partial, cd, ptr_att, y);
}

// Round 19
// 363.738 us; speedup vs baseline: 1.1714x; 1.0385x over previous
//
#include <hip/hip_runtime.h>
#include <hip/hip_fp16.h>

#define B_ 16
#define S_ 12
#define N_ 325
#define E_ 2600
#define CIN_ 32
#define H_ 64
#define HEADS_ 4
#define COUT_ 12
#define BS_ (B_*S_)          // 192
#define ROWS_ (BS_*N_)       // 62400 = 8 * 7800
#define EN_ (E_+N_)          // 2925
#define QK_ 256
#define NCH_ 82              // ceil(N/4)
#define RPX_ 7800            // rows per XCD region (24 bs)

// ---------------- degree / norm / CSR pointers ----------------
__global__ void k_deg(const int* __restrict__ ei, int* __restrict__ ptr_gcn,
                      int* __restrict__ ptr_att, float* __restrict__ dinv) {
  __shared__ int cnt[N_];
  for (int i = threadIdx.x; i < N_; i += blockDim.x) cnt[i] = 0;
  __syncthreads();
  for (int e = threadIdx.x; e < E_; e += blockDim.x)
    atomicAdd(&cnt[ei[E_ + e]], 1);   // col = target
  __syncthreads();
  for (int n = threadIdx.x; n < N_; n += blockDim.x)
    dinv[n] = rsqrtf((float)(cnt[n] + 1));
  if (threadIdx.x == 0) {
    int a = 0, g = 0;
    for (int n = 0; n < N_; n++) {
      ptr_att[n] = a; ptr_gcn[n] = g;
      a += cnt[n]; g += cnt[n] + 1;   // gcn bucket has +1 self-loop slot
    }
    ptr_att[N_] = a; ptr_gcn[N_] = g;
  }
}

// ---------------- deterministic CSR fill (stable rank) ----------------
__global__ void k_fill(const int* __restrict__ ei, const int* __restrict__ ptr_gcn,
                       const int* __restrict__ ptr_att, const float* __restrict__ dinv,
                       int* __restrict__ gcn_src, float* __restrict__ gcn_w,
                       int* __restrict__ att_src) {
  __shared__ int cols[E_];
  for (int i = threadIdx.x; i < E_; i += blockDim.x) cols[i] = ei[E_ + i];
  __syncthreads();
  int e = blockIdx.x * blockDim.x + threadIdx.x;
  if (e >= EN_) return;
  int t = (e < E_) ? cols[e] : (e - E_);
  int s = (e < E_) ? ei[e]   : (e - E_);
  int lim = (e < E_) ? e : E_;
  int rank = 0;
  for (int j = 0; j < lim; j++) rank += (cols[j] == t);
  int pos = ptr_gcn[t] + rank;
  gcn_src[pos] = s;
  gcn_w[pos] = dinv[s] * dinv[t];
  if (e < E_) att_src[ptr_att[t] + rank] = s;
}

// ---------------- setup: AB, cd, Wkt (=G_h^T packed), vvec, c4, zero256 ----------------
__global__ void k_abcd(const float* __restrict__ Wv, const float* __restrict__ Wsm,
                       const float* __restrict__ Wl, const float* __restrict__ bl,
                       const float* __restrict__ bsv, const float* __restrict__ bvv,
                       const float* __restrict__ Wq, const float* __restrict__ bq,
                       const float* __restrict__ Wk, const float* __restrict__ bk,
                       float* __restrict__ AB, float* __restrict__ cd,
                       float* __restrict__ Wkt, float* __restrict__ vc,
                       float* __restrict__ zero256) {
  int t = threadIdx.x;
  if (blockIdx.x < 240) {
    int s = blockIdx.x / 20, dblk = blockIdx.x % 20;
    int dl = t >> 4, co = t & 15;
    int d = dblk * 16 + dl;             // 0..319
    float acc = 0.f;
    if (co < 12) {
      if (d < 256) {
        int h = d >> 6, dd = d & 63;
        for (int j = 0; j < 64; j++)
          acc += Wv[dd * 256 + h * 64 + j] * Wl[(size_t)(s * 256 + h * 64 + j) * 12 + co];
      } else {
        int d0 = d - 256;
        for (int J = 0; J < 256; J++)
          acc += Wsm[d0 * 256 + J] * Wl[(size_t)(s * 256 + J) * 12 + co];
      }
    }
    AB[((size_t)s * 320 + d) * 16 + co] = acc;
  } else if (blockIdx.x == 240) {
    __shared__ float red[2][16][17];
    int co = t & 15, chunk = t >> 4;
    float c = 0.f, dv = 0.f;
    if (co < 12) {
      for (int J = chunk * 192; J < chunk * 192 + 192; J++) {
        float wl = Wl[(size_t)J * 12 + co];
        c  += bsv[J & 255] * wl;
        dv += bvv[J & 255] * wl;
      }
    }
    red[0][chunk][co] = c;
    red[1][chunk][co] = dv;
    __syncthreads();
    if (t < 16) {
      float s0 = 0.f;
      for (int ch = 0; ch < 16; ch++) s0 += red[0][ch][t];
      cd[t] = s0 + ((t < 12) ? bl[t] : 0.f);
    } else if (t < 32) {
      int co2 = t - 16;
      float s1 = 0.f;
      for (int ch = 0; ch < 16; ch++) s1 += red[1][ch][co2];
      cd[16 + co2] = s1;
    }
  } else if (blockIdx.x < 305) {
    // Wkt[e][h*64+d] = G_h[d][e] = sum_i Wq[d][h*64+i] * Wk[e][h*64+i]
    int idx = (blockIdx.x - 241) * 256 + t;    // 0..16383
    int e = idx >> 8, col = idx & 255;
    int h = col >> 6, d = col & 63;
    float acc = 0.f;
    const float* wqr = Wq + (size_t)d * QK_ + h * 64;
    const float* wkr = Wk + (size_t)e * QK_ + h * 64;
#pragma unroll 8
    for (int i = 0; i < 64; i++) acc += wqr[i] * wkr[i];
    Wkt[(size_t)e * QK_ + col] = acc;
  } else {
    int h = t >> 6, e = t & 63;
    float acc = 0.f;
    const float* wkr = Wk + (size_t)e * QK_ + h * 64;
    const float* bqr = bq + h * 64;
#pragma unroll 8
    for (int i = 0; i < 64; i++) acc += wkr[i] * bqr[i];
    vc[t] = acc;
    if (t < 4) {
      float cc = 0.f;
      for (int i = 0; i < 64; i++) cc += bq[t * 64 + i] * bk[t * 64 + i];
      vc[256 + t] = cc;
    }
    zero256[t] = 0.f;
  }
}

// ---------------- GCN aggregation (SpMM), XCD-partitioned ----------------
template<int K>
__global__ __launch_bounds__(256) void k_agg(const float* __restrict__ hin,
    const int* __restrict__ ptr, const int* __restrict__ src,
    const float* __restrict__ wgt, float* __restrict__ ag) {
  int wid = threadIdx.x >> 6, lane = threadIdx.x & 63;
  int bid = blockIdx.x;                  // 15744 = 8 * 1968, 1968 = 24 * 82
  int xcd = bid & 7, sub = bid >> 3;
  int bs = xcd * 24 + sub / NCH_;        // contiguous per XCD
  int n = (sub % NCH_) * 4 + wid;
  if (n >= N_ || (K != 64 && lane >= K)) return;
  int p0 = ptr[n], p1 = ptr[n + 1];
  const float* base = hin + (size_t)bs * N_ * K;
  float a0 = 0.f, a1 = 0.f, a2 = 0.f, a3 = 0.f;
  int e = p0;
  for (; e + 4 <= p1; e += 4) {
    a0 += wgt[e]     * base[src[e]     * K + lane];
    a1 += wgt[e + 1] * base[src[e + 1] * K + lane];
    a2 += wgt[e + 2] * base[src[e + 2] * K + lane];
    a3 += wgt[e + 3] * base[src[e + 3] * K + lane];
  }
  for (; e < p1; ++e) a0 += wgt[e] * base[src[e] * K + lane];
  ag[((size_t)bs * N_ + n) * K + lane] = (a0 + a1) + (a2 + a3);
}

// ---------------- tiled GEMM, BM=64, XCD-partitioned; optional fp16 output ----------------
template<int K, bool RELU, bool BETA, bool OUTH>
__global__ __launch_bounds__(256) void k_gemm(
    const float* __restrict__ A, int M,
    const float* __restrict__ W0, const float* __restrict__ b0, float* __restrict__ C0,
    const float* __restrict__ W1, const float* __restrict__ b1, float* __restrict__ C1,
    int wstride, int cstride, int nct,
    const float* __restrict__ vcp, float* __restrict__ bbout) {
  __shared__ float Ast[K][72];
  __shared__ float Wsh[K][68];
  int t = threadIdx.x;
  int ct = blockIdx.y;
  const float* W   = (ct < nct) ? W0 : W1;
  const float* bia = (ct < nct) ? b0 : b1;
  float* C         = (ct < nct) ? C0 : C1;
  int c0 = (ct & (nct - 1)) * 64;
  for (int i = t; i < K * 64; i += 256)
    Wsh[i >> 6][i & 63] = W[(size_t)(i >> 6) * wstride + c0 + (i & 63)];
  int bid = blockIdx.x;                    // 976 = 8 * 122
  int xcd = bid & 7, sub = bid >> 3;
  int r0 = xcd * RPX_ + sub * 64;
#pragma unroll
  for (int it = 0; it < K / 16; ++it) {
    int idx = it * 256 + t;
    int dq = idx >> 6, rl = idx & 63;
    int ar = min(r0 + rl, M - 1);
    float4 v = *(const float4*)(A + (size_t)ar * K + dq * 4);
    Ast[dq * 4 + 0][rl] = v.x; Ast[dq * 4 + 1][rl] = v.y;
    Ast[dq * 4 + 2][rl] = v.z; Ast[dq * 4 + 3][rl] = v.w;
  }
  __syncthreads();
  int tr = t >> 4, tc = t & 15;
  float acc[4][4];
#pragma unroll
  for (int i = 0; i < 4; i++)
#pragma unroll
    for (int j = 0; j < 4; j++) acc[i][j] = 0.f;
#pragma unroll 8
  for (int k = 0; k < K; k++) {
    float4 w4 = *(const float4*)&Wsh[k][tc * 4];
    float4 a4 = *(const float4*)&Ast[k][tr * 4];
    const float av[4] = {a4.x, a4.y, a4.z, a4.w};
#pragma unroll
    for (int i = 0; i < 4; i++) {
      acc[i][0] += av[i] * w4.x; acc[i][1] += av[i] * w4.y;
      acc[i][2] += av[i] * w4.z; acc[i][3] += av[i] * w4.w;
    }
  }
  float4 b4 = *(const float4*)&bia[c0 + tc * 4];
#pragma unroll
  for (int i = 0; i < 4; i++) {
    int lrow = sub * 64 + tr * 4 + i;      // region-local guard (region = 7800)
    if (lrow < RPX_) {
      int row = r0 + tr * 4 + i;
      float4 o = make_float4(acc[i][0] + b4.x, acc[i][1] + b4.y,
                             acc[i][2] + b4.z, acc[i][3] + b4.w);
      if (RELU) {
        o.x = fmaxf(o.x, 0.f); o.y = fmaxf(o.y, 0.f);
        o.z = fmaxf(o.z, 0.f); o.w = fmaxf(o.w, 0.f);
      }
      if (OUTH) {
        __half* Ch = (__half*)C;
        __half2 p0h = __floats2half2_rn(o.x, o.y);
        __half2 p1h = __floats2half2_rn(o.z, o.w);
        uint2 pk;
        pk.x = *(unsigned int*)&p0h; pk.y = *(unsigned int*)&p1h;
        *(uint2*)(Ch + (size_t)row * cstride + c0 + tc * 4) = pk;
      } else {
        *(float4*)(C + (size_t)row * cstride + c0 + tc * 4) = o;
      }
    }
  }
  if (BETA) {
    if (t < 64) {
      int lrow = sub * 64 + t;
      if (lrow < RPX_) {
        int row = r0 + t;
        float acc2 = vcp[256 + ct];
#pragma unroll 8
        for (int k = 0; k < K; k++) acc2 += Ast[k][t] * vcp[ct * 64 + k];
        bbout[(size_t)row * 4 + ct] = acc2;
      }
    }
  }
}

// ---------------- fused multi-head attention, full-row, XCD-partitioned, fp16 kt ------
__global__ void k_attn4(const __half* __restrict__ kt, const float* __restrict__ xt,
                        const float* __restrict__ bb, const int* __restrict__ ptr,
                        const int* __restrict__ src, __half* __restrict__ zh) {
  __shared__ float xs[4][68];
  __shared__ float wbuf[4][64];
  int wid = threadIdx.x >> 6, lane = threadIdx.x & 63;
  int bid = blockIdx.x;                    // 15600 = 8 * 1950
  int xcd = bid & 7, sub = bid >> 3;
  int g = xcd * RPX_ + sub * 4 + wid;      // 1950*4 = 7800 exact
  int n = g % N_, gbs = g / N_;
  int p0 = ptr[n], p1 = ptr[n + 1];
  const float* xb = xt + (size_t)gbs * N_ * 64;
  xs[wid][lane] = xb[(size_t)n * 64 + lane];   // same-wave write->read
  int h = lane & 3, el = lane >> 2;
  const __half* kb = kt + (size_t)gbs * N_ * QK_;
  const float* bbb = bb + (size_t)gbs * N_ * 4;
  const float4* x4 = reinterpret_cast<const float4*>(&xs[wid][0]);
  float m = -INFINITY, den = 0.f;
  float zacc[4] = {0.f, 0.f, 0.f, 0.f};
  for (int base = p0; base < p1; base += 16) {
    int slot = base + el;
    bool valid = slot < p1;
    int sidx = valid ? src[slot] : 0;
    float logit = -INFINITY;
    if (valid) {
      const uint4* k4h = reinterpret_cast<const uint4*>(kb + (size_t)sidx * QK_ + h * 64);
      float d0 = 0.f, d1 = 0.f;
#pragma unroll
      for (int j = 0; j < 8; j++) {
        uint4 kv = k4h[j];                   // 8 halves
        const __half2* hp = (const __half2*)&kv;
        float2 f0 = __half22float2(hp[0]);
        float2 f1 = __half22float2(hp[1]);
        float2 f2 = __half22float2(hp[2]);
        float2 f3 = __half22float2(hp[3]);
        float4 xa = x4[2 * j], xb2 = x4[2 * j + 1];
        d0 += xa.x * f0.x + xa.y * f0.y + xa.z * f1.x + xa.w * f1.y;
        d1 += xb2.x * f2.x + xb2.y * f2.y + xb2.z * f3.x + xb2.w * f3.y;
      }
      logit = (d0 + d1 + bbb[sidx * 4 + h]) * 0.125f;   // 1/sqrt(64)
    }
    float cm = logit;
#pragma unroll
    for (int o = 4; o < 64; o <<= 1) cm = fmaxf(cm, __shfl_xor(cm, o));
    float mnew = fmaxf(m, cm);
    float scale = __expf(m - mnew);        // first chunk: exp(-inf)=0
    float w = valid ? __expf(logit - mnew) : 0.f;
    float wsum = w;
#pragma unroll
    for (int o = 4; o < 64; o <<= 1) wsum += __shfl_xor(wsum, o);
    den = den * scale + wsum;
    wbuf[wid][lane] = w;                   // same-wave DS order
#pragma unroll
    for (int h2 = 0; h2 < 4; h2++) zacc[h2] *= __shfl(scale, h2);
    int cnt = min(16, p1 - base);
    for (int e2 = 0; e2 < cnt; e2++) {
      int s_e = __shfl(sidx, e2 * 4);
      float xv = xb[(size_t)s_e * 64 + lane];
      float4 w4 = *(const float4*)&wbuf[wid][e2 * 4];  // broadcast, conflict-free
      zacc[0] += w4.x * xv; zacc[1] += w4.y * xv;
      zacc[2] += w4.z * xv; zacc[3] += w4.w * xv;
    }
    m = mnew;
  }
  bool ok = p1 > p0;
#pragma unroll
  for (int h2 = 0; h2 < 4; h2++) {
    float dh = __shfl(den, h2);
    zh[(size_t)g * QK_ + h2 * 64 + lane] =
        __float2half(ok ? zacc[h2] / (dh + 1e-16f) : 0.f);
  }
}

// ---------------- thin GEMM, XCD-partitioned: partial = [z|xt](320) @ AB_s(320x12) ------
__global__ __launch_bounds__(256) void k_fin(const __half* __restrict__ zh,
    const float* __restrict__ xt, const float* __restrict__ AB,
    float* __restrict__ partial) {
  __shared__ float Zs[32][327];
  __shared__ float ABs[320][16];
  int t = threadIdx.x;
  int bid = blockIdx.x;              // 2112 = 8 * 264, 264 = 24 * 11
  int xcd = bid & 7, sub = bid >> 3;
  int bs = xcd * 24 + sub / 11;
  int n0 = (sub % 11) * 32;
  int s = bs % 12;
  const float4* ABg = (const float4*)(AB + (size_t)s * 320 * 16);
  for (int i = t; i < 320 * 4; i += 256) ((float4*)ABs)[i] = ABg[i];
  for (int i = t; i < 2560; i += 256) {
    int rl = i / 80, dq = i % 80;
    int n = min(n0 + rl, N_ - 1);
    size_t row = (size_t)bs * N_ + n;
    float4 v;
    if (dq < 64) {
      const __half2* zp = (const __half2*)(zh + row * QK_ + dq * 4);
      __half2 ha = zp[0], hb = zp[1];
      v = make_float4(__low2float(ha), __high2float(ha),
                      __low2float(hb), __high2float(hb));
    } else {
      v = ((const float4*)xt)[row * 16 + (dq - 64)];
    }
    int d0 = dq * 4;
    Zs[rl][d0] = v.x; Zs[rl][d0 + 1] = v.y; Zs[rl][d0 + 2] = v.z; Zs[rl][d0 + 3] = v.w;
  }
  __syncthreads();
  float acc[4][4];
#pragma unroll
  for (int i = 0; i < 4; i++)
#pragma unroll
    for (int j = 0; j < 4; j++) acc[i][j] = 0.f;
  int rg = t & 7, tmp = t >> 3;
  int cg = tmp % 3, dc = tmp / 3;
  if (dc < 10) {
    int dbase = dc * 32;
    for (int dd = 0; dd < 32; dd++) {
      int d = dbase + dd;
      float4 ab = *(const float4*)&ABs[d][cg * 4];
      float a0 = Zs[rg * 4 + 0][d], a1 = Zs[rg * 4 + 1][d];
      float a2 = Zs[rg * 4 + 2][d], a3 = Zs[rg * 4 + 3][d];
      acc[0][0] += a0 * ab.x; acc[0][1] += a0 * ab.y; acc[0][2] += a0 * ab.z; acc[0][3] += a0 * ab.w;
      acc[1][0] += a1 * ab.x; acc[1][1] += a1 * ab.y; acc[1][2] += a1 * ab.z; acc[1][3] += a1 * ab.w;
      acc[2][0] += a2 * ab.x; acc[2][1] += a2 * ab.y; acc[2][2] += a2 * ab.z; acc[2][3] += a2 * ab.w;
      acc[3][0] += a3 * ab.x; acc[3][1] += a3 * ab.y; acc[3][2] += a3 * ab.z; acc[3][3] += a3 * ab.w;
    }
  }
  __syncthreads();
  float* red = &Zs[0][0];
  if (dc < 10) {
    int base = (((rg * 3 + cg) * 10) + dc) * 16;
#pragma unroll
    for (int i = 0; i < 4; i++)
      *(float4*)&red[base + i * 4] = make_float4(acc[i][0], acc[i][1], acc[i][2], acc[i][3]);
  }
  __syncthreads();
  for (int o = t; o < 384; o += 256) {
    int r = o / 12, co = o % 12;
    int rg2 = r >> 2, i2 = r & 3, cg2 = co >> 2, j2 = co & 3;
    float s0 = 0.f;
#pragma unroll
    for (int d2 = 0; d2 < 10; d2++)
      s0 += red[(((rg2 * 3 + cg2) * 10) + d2) * 16 + i2 * 4 + j2];
    int n = n0 + r;
    if (n < N_)
      partial[((size_t)bs * N_ + n) * 12 + co] = s0;
  }
}

// ---------------- y = sum_s partial + cvec + 1{deg>0} dvec ----------------
__global__ void k_red(const float* __restrict__ partial, const float* __restrict__ cd,
                      const int* __restrict__ ptr, float* __restrict__ y) {
  int tg = blockIdx.x * 256 + threadIdx.x;
  if (tg >= B_ * N_ * 12) return;
  int bn = tg / 12, co = tg % 12;
  int b = bn / N_, n = bn % N_;
  float acc = cd[co];
  if (ptr[n + 1] > ptr[n]) acc += cd[16 + co];
  for (int s = 0; s < 12; s++)
    acc += partial[(((size_t)(b * 12 + s)) * N_ + n) * 12 + co];
  y[(size_t)bn * 12 + co] = acc;
}

extern "C" void kernel_launch(void* const* d_in, const int* in_sizes, int n_in,
                              void* d_out, int out_size, void* d_ws, size_t ws_size,
                              hipStream_t stream) {
  const float* x   = (const float*)d_in[0];
  const int*   ei  = (const int*)d_in[1];
  const float* Wg[4] = {(const float*)d_in[2], (const float*)d_in[4],
                        (const float*)d_in[6], (const float*)d_in[8]};
  const float* bg[4] = {(const float*)d_in[3], (const float*)d_in[5],
                        (const float*)d_in[7], (const float*)d_in[9]};
  const float* Wq = (const float*)d_in[10]; const float* bq = (const float*)d_in[11];
  const float* Wk = (const float*)d_in[12]; const float* bk = (const float*)d_in[13];
  const float* Wv = (const float*)d_in[14]; const float* bv = (const float*)d_in[15];
  const float* Ws = (const float*)d_in[16]; const float* bs = (const float*)d_in[17];
  const float* Wl = (const float*)d_in[18]; const float* bl = (const float*)d_in[19];
  float* y = (float*)d_out;

  char* p = (char*)d_ws;
  auto alloc = [&](size_t bytes) {
    char* r = p;
    p += (bytes + 255) & ~(size_t)255;
    return r;
  };
  float* dinv    = (float*)alloc(N_ * 4);
  int*   ptr_gcn = (int*)alloc((N_ + 1) * 4);
  int*   ptr_att = (int*)alloc((N_ + 1) * 4);
  int*   gcn_src = (int*)alloc(EN_ * 4);
  float* gcn_w   = (float*)alloc(EN_ * 4);
  int*   att_src = (int*)alloc(E_ * 4);
  float* AB      = (float*)alloc((size_t)12 * 320 * 16 * 4);  // 245 KB
  float* cd      = (float*)alloc(32 * 4);
  float* Wkt     = (float*)alloc((size_t)64 * QK_ * 4);       // 64 KB
  float* vc      = (float*)alloc(260 * 4);
  float* zero256 = (float*)alloc(256 * 4);
  float* bb      = (float*)alloc((size_t)ROWS_ * 4 * 4);      // 1 MB
  // ktb (32 MB fp16 full-row) aliases [ag | h0] — both dead after GCN.
  float* ag  = (float*)alloc((size_t)ROWS_ * H_ * 4);      // 16 MB
  float* h0  = (float*)alloc((size_t)ROWS_ * H_ * 4);      // 16 MB (contiguous after ag)
  __half* ktb = (__half*)ag;                               // 32 MB spans ag+h0
  float* h1  = (float*)alloc((size_t)ROWS_ * H_ * 4);      // 16 MB (xt)
  __half* zh = (__half*)alloc((size_t)ROWS_ * QK_ * 2);    // 32 MB (fp16 z)
  float* partial = (float*)alloc((size_t)ROWS_ * 12 * 4);  // 3 MB
  (void)ws_size; (void)in_sizes; (void)n_in; (void)out_size;

  k_deg<<<1, 512, 0, stream>>>(ei, ptr_gcn, ptr_att, dinv);
  k_fill<<<(EN_ + 255) / 256, 256, 0, stream>>>(ei, ptr_gcn, ptr_att, dinv,
                                                gcn_src, gcn_w, att_src);
  k_abcd<<<306, 256, 0, stream>>>(Wv, Ws, Wl, bl, bs, bv, Wq, bq, Wk, bk,
                                  AB, cd, Wkt, vc, zero256);

  // GCN layers: agg (SpMM) + tiled GEMM, both XCD-partitioned, ping-pong
  int agrid = 8 * 24 * NCH_;        // 15744
  int ggrid = 8 * 122;              // 976 (122*64 covers 7800-row region)
  k_agg<CIN_><<<agrid, 256, 0, stream>>>(x, ptr_gcn, gcn_src, gcn_w, ag);
  k_gemm<CIN_, true, false, false><<<dim3(ggrid, 1), 256, 0, stream>>>(
      ag, ROWS_, Wg[0], bg[0], h0, Wg[0], bg[0], h0, 64, 64, 1, nullptr, nullptr);
  k_agg<H_><<<agrid, 256, 0, stream>>>(h0, ptr_gcn, gcn_src, gcn_w, ag);
  k_gemm<H_, true, false, false><<<dim3(ggrid, 1), 256, 0, stream>>>(
      ag, ROWS_, Wg[1], bg[1], h1, Wg[1], bg[1], h1, 64, 64, 1, nullptr, nullptr);
  k_agg<H_><<<agrid, 256, 0, stream>>>(h1, ptr_gcn, gcn_src, gcn_w, ag);
  k_gemm<H_, true, false, false><<<dim3(ggrid, 1), 256, 0, stream>>>(
      ag, ROWS_, Wg[2], bg[2], h0, Wg[2], bg[2], h0, 64, 64, 1, nullptr, nullptr);
  k_agg<H_><<<agrid, 256, 0, stream>>>(h0, ptr_gcn, gcn_src, gcn_w, ag);
  k_gemm<H_, true, false, false><<<dim3(ggrid, 1), 256, 0, stream>>>(
      ag, ROWS_, Wg[3], bg[3], h1, Wg[3], bg[3], h1, 64, 64, 1, nullptr, nullptr);

  // kt = xt @ Wkt over ALL rows (fp16 output); beta fused into epilogue
  k_gemm<H_, false, true, true><<<dim3(ggrid, 4), 256, 0, stream>>>(
      h1, ROWS_, Wkt, zero256, (float*)ktb, Wkt, zero256, (float*)ktb,
      QK_, QK_, 4, vc, bb);

  // attention + fin, single full-row XCD-aligned launches
  k_attn4<<<8 * (RPX_ / 4), 256, 0, stream>>>(ktb, h1, bb, ptr_att, att_src, zh);
  k_fin<<<8 * 24 * 11, 256, 0, stream>>>(zh, h1, AB, partial);

  k_red<<<(B_ * N_ * 12 + 255) / 256, 256, 0, stream>>>(partial, cd, ptr_att, y);
}

// Round 20
// 337.597 us; speedup vs baseline: 1.2621x; 1.0774x over previous
//
#include <hip/hip_runtime.h>
#include <hip/hip_fp16.h>

#define B_ 16
#define S_ 12
#define N_ 325
#define E_ 2600
#define CIN_ 32
#define H_ 64
#define HEADS_ 4
#define COUT_ 12
#define BS_ (B_*S_)          // 192
#define ROWS_ (BS_*N_)       // 62400 = 8 * 7800
#define EN_ (E_+N_)          // 2925
#define QK_ 256
#define NCH_ 82              // ceil(N/4)
#define RPX_ 7800            // rows per XCD region (24 bs)

typedef _Float16 h2v __attribute__((ext_vector_type(2)));

#if defined(__has_builtin)
#if __has_builtin(__builtin_amdgcn_fdot2)
#define HAS_FDOT2 1
#endif
#endif

__device__ __forceinline__ float fdot2u(unsigned int a, unsigned int b, float c) {
#ifdef HAS_FDOT2
  return __builtin_amdgcn_fdot2(__builtin_bit_cast(h2v, a),
                                __builtin_bit_cast(h2v, b), c, false);
#else
  __half2 ah = *reinterpret_cast<__half2*>(&a);
  __half2 bh = *reinterpret_cast<__half2*>(&b);
  float2 fa = __half22float2(ah), fb = __half22float2(bh);
  return c + fa.x * fb.x + fa.y * fb.y;
#endif
}

// ---------------- degree / norm / CSR pointers ----------------
__global__ void k_deg(const int* __restrict__ ei, int* __restrict__ ptr_gcn,
                      int* __restrict__ ptr_att, float* __restrict__ dinv) {
  __shared__ int cnt[N_];
  for (int i = threadIdx.x; i < N_; i += blockDim.x) cnt[i] = 0;
  __syncthreads();
  for (int e = threadIdx.x; e < E_; e += blockDim.x)
    atomicAdd(&cnt[ei[E_ + e]], 1);   // col = target
  __syncthreads();
  for (int n = threadIdx.x; n < N_; n += blockDim.x)
    dinv[n] = rsqrtf((float)(cnt[n] + 1));
  if (threadIdx.x == 0) {
    int a = 0, g = 0;
    for (int n = 0; n < N_; n++) {
      ptr_att[n] = a; ptr_gcn[n] = g;
      a += cnt[n]; g += cnt[n] + 1;   // gcn bucket has +1 self-loop slot
    }
    ptr_att[N_] = a; ptr_gcn[N_] = g;
  }
}

// ---------------- deterministic CSR fill (stable rank) ----------------
__global__ void k_fill(const int* __restrict__ ei, const int* __restrict__ ptr_gcn,
                       const int* __restrict__ ptr_att, const float* __restrict__ dinv,
                       int* __restrict__ gcn_src, float* __restrict__ gcn_w,
                       int* __restrict__ att_src) {
  __shared__ int cols[E_];
  for (int i = threadIdx.x; i < E_; i += blockDim.x) cols[i] = ei[E_ + i];
  __syncthreads();
  int e = blockIdx.x * blockDim.x + threadIdx.x;
  if (e >= EN_) return;
  int t = (e < E_) ? cols[e] : (e - E_);
  int s = (e < E_) ? ei[e]   : (e - E_);
  int lim = (e < E_) ? e : E_;
  int rank = 0;
  for (int j = 0; j < lim; j++) rank += (cols[j] == t);
  int pos = ptr_gcn[t] + rank;
  gcn_src[pos] = s;
  gcn_w[pos] = dinv[s] * dinv[t];
  if (e < E_) att_src[ptr_att[t] + rank] = s;
}

// ---------------- setup: AB, cd, Wkt (=G_h^T packed), vvec, c4, zero256 ----------------
__global__ void k_abcd(const float* __restrict__ Wv, const float* __restrict__ Wsm,
                       const float* __restrict__ Wl, const float* __restrict__ bl,
                       const float* __restrict__ bsv, const float* __restrict__ bvv,
                       const float* __restrict__ Wq, const float* __restrict__ bq,
                       const float* __restrict__ Wk, const float* __restrict__ bk,
                       float* __restrict__ AB, float* __restrict__ cd,
                       float* __restrict__ Wkt, float* __restrict__ vc,
                       float* __restrict__ zero256) {
  int t = threadIdx.x;
  if (blockIdx.x < 240) {
    int s = blockIdx.x / 20, dblk = blockIdx.x % 20;
    int dl = t >> 4, co = t & 15;
    int d = dblk * 16 + dl;             // 0..319
    float acc = 0.f;
    if (co < 12) {
      if (d < 256) {
        int h = d >> 6, dd = d & 63;
        for (int j = 0; j < 64; j++)
          acc += Wv[dd * 256 + h * 64 + j] * Wl[(size_t)(s * 256 + h * 64 + j) * 12 + co];
      } else {
        int d0 = d - 256;
        for (int J = 0; J < 256; J++)
          acc += Wsm[d0 * 256 + J] * Wl[(size_t)(s * 256 + J) * 12 + co];
      }
    }
    AB[((size_t)s * 320 + d) * 16 + co] = acc;
  } else if (blockIdx.x == 240) {
    __shared__ float red[2][16][17];
    int co = t & 15, chunk = t >> 4;
    float c = 0.f, dv = 0.f;
    if (co < 12) {
      for (int J = chunk * 192; J < chunk * 192 + 192; J++) {
        float wl = Wl[(size_t)J * 12 + co];
        c  += bsv[J & 255] * wl;
        dv += bvv[J & 255] * wl;
      }
    }
    red[0][chunk][co] = c;
    red[1][chunk][co] = dv;
    __syncthreads();
    if (t < 16) {
      float s0 = 0.f;
      for (int ch = 0; ch < 16; ch++) s0 += red[0][ch][t];
      cd[t] = s0 + ((t < 12) ? bl[t] : 0.f);
    } else if (t < 32) {
      int co2 = t - 16;
      float s1 = 0.f;
      for (int ch = 0; ch < 16; ch++) s1 += red[1][ch][co2];
      cd[16 + co2] = s1;
    }
  } else if (blockIdx.x < 305) {
    // Wkt[e][h*64+d] = G_h[d][e] = sum_i Wq[d][h*64+i] * Wk[e][h*64+i]
    int idx = (blockIdx.x - 241) * 256 + t;    // 0..16383
    int e = idx >> 8, col = idx & 255;
    int h = col >> 6, d = col & 63;
    float acc = 0.f;
    const float* wqr = Wq + (size_t)d * QK_ + h * 64;
    const float* wkr = Wk + (size_t)e * QK_ + h * 64;
#pragma unroll 8
    for (int i = 0; i < 64; i++) acc += wqr[i] * wkr[i];
    Wkt[(size_t)e * QK_ + col] = acc;
  } else {
    int h = t >> 6, e = t & 63;
    float acc = 0.f;
    const float* wkr = Wk + (size_t)e * QK_ + h * 64;
    const float* bqr = bq + h * 64;
#pragma unroll 8
    for (int i = 0; i < 64; i++) acc += wkr[i] * bqr[i];
    vc[t] = acc;
    if (t < 4) {
      float cc = 0.f;
      for (int i = 0; i < 64; i++) cc += bq[t * 64 + i] * bk[t * 64 + i];
      vc[256 + t] = cc;
    }
    zero256[t] = 0.f;
  }
}

// ---------------- GCN aggregation (SpMM), XCD-partitioned ----------------
template<int K>
__global__ __launch_bounds__(256) void k_agg(const float* __restrict__ hin,
    const int* __restrict__ ptr, const int* __restrict__ src,
    const float* __restrict__ wgt, float* __restrict__ ag) {
  int wid = threadIdx.x >> 6, lane = threadIdx.x & 63;
  int bid = blockIdx.x;                  // 15744 = 8 * 1968, 1968 = 24 * 82
  int xcd = bid & 7, sub = bid >> 3;
  int bs = xcd * 24 + sub / NCH_;        // contiguous per XCD
  int n = (sub % NCH_) * 4 + wid;
  if (n >= N_ || (K != 64 && lane >= K)) return;
  int p0 = ptr[n], p1 = ptr[n + 1];
  const float* base = hin + (size_t)bs * N_ * K;
  float a0 = 0.f, a1 = 0.f, a2 = 0.f, a3 = 0.f;
  int e = p0;
  for (; e + 4 <= p1; e += 4) {
    a0 += wgt[e]     * base[src[e]     * K + lane];
    a1 += wgt[e + 1] * base[src[e + 1] * K + lane];
    a2 += wgt[e + 2] * base[src[e + 2] * K + lane];
    a3 += wgt[e + 3] * base[src[e + 3] * K + lane];
  }
  for (; e < p1; ++e) a0 += wgt[e] * base[src[e] * K + lane];
  ag[((size_t)bs * N_ + n) * K + lane] = (a0 + a1) + (a2 + a3);
}

// ---------------- tiled GEMM, BM=64, XCD-partitioned; optional fp16 output ----------------
template<int K, bool RELU, bool BETA, bool OUTH>
__global__ __launch_bounds__(256) void k_gemm(
    const float* __restrict__ A, int M,
    const float* __restrict__ W0, const float* __restrict__ b0, float* __restrict__ C0,
    const float* __restrict__ W1, const float* __restrict__ b1, float* __restrict__ C1,
    int wstride, int cstride, int nct,
    const float* __restrict__ vcp, float* __restrict__ bbout) {
  __shared__ float Ast[K][72];
  __shared__ float Wsh[K][68];
  int t = threadIdx.x;
  int ct = blockIdx.y;
  const float* W   = (ct < nct) ? W0 : W1;
  const float* bia = (ct < nct) ? b0 : b1;
  float* C         = (ct < nct) ? C0 : C1;
  int c0 = (ct & (nct - 1)) * 64;
  for (int i = t; i < K * 64; i += 256)
    Wsh[i >> 6][i & 63] = W[(size_t)(i >> 6) * wstride + c0 + (i & 63)];
  int bid = blockIdx.x;                    // 976 = 8 * 122
  int xcd = bid & 7, sub = bid >> 3;
  int r0 = xcd * RPX_ + sub * 64;
#pragma unroll
  for (int it = 0; it < K / 16; ++it) {
    int idx = it * 256 + t;
    int dq = idx >> 6, rl = idx & 63;
    int ar = min(r0 + rl, M - 1);
    float4 v = *(const float4*)(A + (size_t)ar * K + dq * 4);
    Ast[dq * 4 + 0][rl] = v.x; Ast[dq * 4 + 1][rl] = v.y;
    Ast[dq * 4 + 2][rl] = v.z; Ast[dq * 4 + 3][rl] = v.w;
  }
  __syncthreads();
  int tr = t >> 4, tc = t & 15;
  float acc[4][4];
#pragma unroll
  for (int i = 0; i < 4; i++)
#pragma unroll
    for (int j = 0; j < 4; j++) acc[i][j] = 0.f;
#pragma unroll 8
  for (int k = 0; k < K; k++) {
    float4 w4 = *(const float4*)&Wsh[k][tc * 4];
    float4 a4 = *(const float4*)&Ast[k][tr * 4];
    const float av[4] = {a4.x, a4.y, a4.z, a4.w};
#pragma unroll
    for (int i = 0; i < 4; i++) {
      acc[i][0] += av[i] * w4.x; acc[i][1] += av[i] * w4.y;
      acc[i][2] += av[i] * w4.z; acc[i][3] += av[i] * w4.w;
    }
  }
  float4 b4 = *(const float4*)&bia[c0 + tc * 4];
#pragma unroll
  for (int i = 0; i < 4; i++) {
    int lrow = sub * 64 + tr * 4 + i;      // region-local guard (region = 7800)
    if (lrow < RPX_) {
      int row = r0 + tr * 4 + i;
      float4 o = make_float4(acc[i][0] + b4.x, acc[i][1] + b4.y,
                             acc[i][2] + b4.z, acc[i][3] + b4.w);
      if (RELU) {
        o.x = fmaxf(o.x, 0.f); o.y = fmaxf(o.y, 0.f);
        o.z = fmaxf(o.z, 0.f); o.w = fmaxf(o.w, 0.f);
      }
      if (OUTH) {
        __half* Ch = (__half*)C;
        __half2 p0h = __floats2half2_rn(o.x, o.y);
        __half2 p1h = __floats2half2_rn(o.z, o.w);
        uint2 pk;
        pk.x = *(unsigned int*)&p0h; pk.y = *(unsigned int*)&p1h;
        *(uint2*)(Ch + (size_t)row * cstride + c0 + tc * 4) = pk;
      } else {
        *(float4*)(C + (size_t)row * cstride + c0 + tc * 4) = o;
      }
    }
  }
  if (BETA) {
    if (t < 64) {
      int lrow = sub * 64 + t;
      if (lrow < RPX_) {
        int row = r0 + t;
        float acc2 = vcp[256 + ct];
#pragma unroll 8
        for (int k = 0; k < K; k++) acc2 += Ast[k][t] * vcp[ct * 64 + k];
        bbout[(size_t)row * 4 + ct] = acc2;
      }
    }
  }
}

// ---------------- fused multi-head attention: fp16 kt + fp16 x, v_dot2_f32_f16 ------
__global__ void k_attn4(const __half* __restrict__ kt, const float* __restrict__ xt,
                        const float* __restrict__ bb, const int* __restrict__ ptr,
                        const int* __restrict__ src, __half* __restrict__ zh) {
  __shared__ __half xsh[4][64];            // 128B rows, aligned for uint4 reads
  __shared__ float wbuf[4][64];
  int wid = threadIdx.x >> 6, lane = threadIdx.x & 63;
  int bid = blockIdx.x;                    // 15600 = 8 * 1950
  int xcd = bid & 7, sub = bid >> 3;
  int g = xcd * RPX_ + sub * 4 + wid;      // 1950*4 = 7800 exact
  int n = g % N_, gbs = g / N_;
  int p0 = ptr[n], p1 = ptr[n + 1];
  const float* xb = xt + (size_t)gbs * N_ * 64;
  xsh[wid][lane] = __float2half(xb[(size_t)n * 64 + lane]);  // same-wave write->read
  int h = lane & 3, el = lane >> 2;
  const __half* kb = kt + (size_t)gbs * N_ * QK_;
  const float* bbb = bb + (size_t)gbs * N_ * 4;
  const uint4* x4h = reinterpret_cast<const uint4*>(&xsh[wid][0]);  // 8 x 8 halves
  float m = -INFINITY, den = 0.f;
  float zacc[4] = {0.f, 0.f, 0.f, 0.f};
  for (int base = p0; base < p1; base += 16) {
    int slot = base + el;
    bool valid = slot < p1;
    int sidx = valid ? src[slot] : 0;
    float logit = -INFINITY;
    if (valid) {
      const uint4* k4h = reinterpret_cast<const uint4*>(kb + (size_t)sidx * QK_ + h * 64);
      float d0 = 0.f, d1 = 0.f;
#pragma unroll
      for (int j = 0; j < 4; j++) {
        uint4 kv = k4h[2 * j],     xv = x4h[2 * j];
        uint4 kv2 = k4h[2 * j + 1], xv2 = x4h[2 * j + 1];
        d0 = fdot2u(kv.x, xv.x, d0);  d0 = fdot2u(kv.y, xv.y, d0);
        d0 = fdot2u(kv.z, xv.z, d0);  d0 = fdot2u(kv.w, xv.w, d0);
        d1 = fdot2u(kv2.x, xv2.x, d1); d1 = fdot2u(kv2.y, xv2.y, d1);
        d1 = fdot2u(kv2.z, xv2.z, d1); d1 = fdot2u(kv2.w, xv2.w, d1);
      }
      logit = (d0 + d1 + bbb[sidx * 4 + h]) * 0.125f;   // 1/sqrt(64)
    }
    float cm = logit;
#pragma unroll
    for (int o = 4; o < 64; o <<= 1) cm = fmaxf(cm, __shfl_xor(cm, o));
    float mnew = fmaxf(m, cm);
    float scale = __expf(m - mnew);        // first chunk: exp(-inf)=0
    float w = valid ? __expf(logit - mnew) : 0.f;
    float wsum = w;
#pragma unroll
    for (int o = 4; o < 64; o <<= 1) wsum += __shfl_xor(wsum, o);
    den = den * scale + wsum;
    wbuf[wid][lane] = w;                   // same-wave DS order
#pragma unroll
    for (int h2 = 0; h2 < 4; h2++) zacc[h2] *= __shfl(scale, h2);
    int cnt = min(16, p1 - base);
    for (int e2 = 0; e2 < cnt; e2++) {
      int s_e = __shfl(sidx, e2 * 4);
      float xv = xb[(size_t)s_e * 64 + lane];
      float4 w4 = *(const float4*)&wbuf[wid][e2 * 4];  // broadcast, conflict-free
      zacc[0] += w4.x * xv; zacc[1] += w4.y * xv;
      zacc[2] += w4.z * xv; zacc[3] += w4.w * xv;
    }
    m = mnew;
  }
  bool ok = p1 > p0;
#pragma unroll
  for (int h2 = 0; h2 < 4; h2++) {
    float dh = __shfl(den, h2);
    zh[(size_t)g * QK_ + h2 * 64 + lane] =
        __float2half(ok ? zacc[h2] / (dh + 1e-16f) : 0.f);
  }
}

// ---------------- thin GEMM, XCD-partitioned: partial = [z|xt](320) @ AB_s(320x12) ------
__global__ __launch_bounds__(256) void k_fin(const __half* __restrict__ zh,
    const float* __restrict__ xt, const float* __restrict__ AB,
    float* __restrict__ partial) {
  __shared__ float Zs[32][327];
  __shared__ float ABs[320][16];
  int t = threadIdx.x;
  int bid = blockIdx.x;              // 2112 = 8 * 264, 264 = 24 * 11
  int xcd = bid & 7, sub = bid >> 3;
  int bs = xcd * 24 + sub / 11;
  int n0 = (sub % 11) * 32;
  int s = bs % 12;
  const float4* ABg = (const float4*)(AB + (size_t)s * 320 * 16);
  for (int i = t; i < 320 * 4; i += 256) ((float4*)ABs)[i] = ABg[i];
  for (int i = t; i < 2560; i += 256) {
    int rl = i / 80, dq = i % 80;
    int n = min(n0 + rl, N_ - 1);
    size_t row = (size_t)bs * N_ + n;
    float4 v;
    if (dq < 64) {
      const __half2* zp = (const __half2*)(zh + row * QK_ + dq * 4);
      __half2 ha = zp[0], hb = zp[1];
      v = make_float4(__low2float(ha), __high2float(ha),
                      __low2float(hb), __high2float(hb));
    } else {
      v = ((const float4*)xt)[row * 16 + (dq - 64)];
    }
    int d0 = dq * 4;
    Zs[rl][d0] = v.x; Zs[rl][d0 + 1] = v.y; Zs[rl][d0 + 2] = v.z; Zs[rl][d0 + 3] = v.w;
  }
  __syncthreads();
  float acc[4][4];
#pragma unroll
  for (int i = 0; i < 4; i++)
#pragma unroll
    for (int j = 0; j < 4; j++) acc[i][j] = 0.f;
  int rg = t & 7, tmp = t >> 3;
  int cg = tmp % 3, dc = tmp / 3;
  if (dc < 10) {
    int dbase = dc * 32;
    for (int dd = 0; dd < 32; dd++) {
      int d = dbase + dd;
      float4 ab = *(const float4*)&ABs[d][cg * 4];
      float a0 = Zs[rg * 4 + 0][d], a1 = Zs[rg * 4 + 1][d];
      float a2 = Zs[rg * 4 + 2][d], a3 = Zs[rg * 4 + 3][d];
      acc[0][0] += a0 * ab.x; acc[0][1] += a0 * ab.y; acc[0][2] += a0 * ab.z; acc[0][3] += a0 * ab.w;
      acc[1][0] += a1 * ab.x; acc[1][1] += a1 * ab.y; acc[1][2] += a1 * ab.z; acc[1][3] += a1 * ab.w;
      acc[2][0] += a2 * ab.x; acc[2][1] += a2 * ab.y; acc[2][2] += a2 * ab.z; acc[2][3] += a2 * ab.w;
      acc[3][0] += a3 * ab.x; acc[3][1] += a3 * ab.y; acc[3][2] += a3 * ab.z; acc[3][3] += a3 * ab.w;
    }
  }
  __syncthreads();
  float* red = &Zs[0][0];
  if (dc < 10) {
    int base = (((rg * 3 + cg) * 10) + dc) * 16;
#pragma unroll
    for (int i = 0; i < 4; i++)
      *(float4*)&red[base + i * 4] = make_float4(acc[i][0], acc[i][1], acc[i][2], acc[i][3]);
  }
  __syncthreads();
  for (int o = t; o < 384; o += 256) {
    int r = o / 12, co = o % 12;
    int rg2 = r >> 2, i2 = r & 3, cg2 = co >> 2, j2 = co & 3;
    float s0 = 0.f;
#pragma unroll
    for (int d2 = 0; d2 < 10; d2++)
      s0 += red[(((rg2 * 3 + cg2) * 10) + d2) * 16 + i2 * 4 + j2];
    int n = n0 + r;
    if (n < N_)
      partial[((size_t)bs * N_ + n) * 12 + co] = s0;
  }
}

// ---------------- y = sum_s partial + cvec + 1{deg>0} dvec ----------------
__global__ void k_red(const float* __restrict__ partial, const float* __restrict__ cd,
                      const int* __restrict__ ptr, float* __restrict__ y) {
  int tg = blockIdx.x * 256 + threadIdx.x;
  if (tg >= B_ * N_ * 12) return;
  int bn = tg / 12, co = tg % 12;
  int b = bn / N_, n = bn % N_;
  float acc = cd[co];
  if (ptr[n + 1] > ptr[n]) acc += cd[16 + co];
  for (int s = 0; s < 12; s++)
    acc += partial[(((size_t)(b * 12 + s)) * N_ + n) * 12 + co];
  y[(size_t)bn * 12 + co] = acc;
}

extern "C" void kernel_launch(void* const* d_in, const int* in_sizes, int n_in,
                              void* d_out, int out_size, void* d_ws, size_t ws_size,
                              hipStream_t stream) {
  const float* x   = (const float*)d_in[0];
  const int*   ei  = (const int*)d_in[1];
  const float* Wg[4] = {(const float*)d_in[2], (const float*)d_in[4],
                        (const float*)d_in[6], (const float*)d_in[8]};
  const float* bg[4] = {(const float*)d_in[3], (const float*)d_in[5],
                        (const float*)d_in[7], (const float*)d_in[9]};
  const float* Wq = (const float*)d_in[10]; const float* bq = (const float*)d_in[11];
  const float* Wk = (const float*)d_in[12]; const float* bk = (const float*)d_in[13];
  const float* Wv = (const float*)d_in[14]; const float* bv = (const float*)d_in[15];
  const float* Ws = (const float*)d_in[16]; const float* bs = (const float*)d_in[17];
  const float* Wl = (const float*)d_in[18]; const float* bl = (const float*)d_in[19];
  float* y = (float*)d_out;

  char* p = (char*)d_ws;
  auto alloc = [&](size_t bytes) {
    char* r = p;
    p += (bytes + 255) & ~(size_t)255;
    return r;
  };
  float* dinv    = (float*)alloc(N_ * 4);
  int*   ptr_gcn = (int*)alloc((N_ + 1) * 4);
  int*   ptr_att = (int*)alloc((N_ + 1) * 4);
  int*   gcn_src = (int*)alloc(EN_ * 4);
  float* gcn_w   = (float*)alloc(EN_ * 4);
  int*   att_src = (int*)alloc(E_ * 4);
  float* AB      = (float*)alloc((size_t)12 * 320 * 16 * 4);  // 245 KB
  float* cd      = (float*)alloc(32 * 4);
  float* Wkt     = (float*)alloc((size_t)64 * QK_ * 4);       // 64 KB
  float* vc      = (float*)alloc(260 * 4);
  float* zero256 = (float*)alloc(256 * 4);
  float* bb      = (float*)alloc((size_t)ROWS_ * 4 * 4);      // 1 MB
  // ktb (32 MB fp16 full-row) aliases [ag | h0] — both dead after GCN.
  float* ag  = (float*)alloc((size_t)ROWS_ * H_ * 4);      // 16 MB
  float* h0  = (float*)alloc((size_t)ROWS_ * H_ * 4);      // 16 MB (contiguous after ag)
  __half* ktb = (__half*)ag;                               // 32 MB spans ag+h0
  float* h1  = (float*)alloc((size_t)ROWS_ * H_ * 4);      // 16 MB (xt)
  __half* zh = (__half*)alloc((size_t)ROWS_ * QK_ * 2);    // 32 MB (fp16 z)
  float* partial = (float*)alloc((size_t)ROWS_ * 12 * 4);  // 3 MB
  (void)ws_size; (void)in_sizes; (void)n_in; (void)out_size;

  k_deg<<<1, 512, 0, stream>>>(ei, ptr_gcn, ptr_att, dinv);
  k_fill<<<(EN_ + 255) / 256, 256, 0, stream>>>(ei, ptr_gcn, ptr_att, dinv,
                                                gcn_src, gcn_w, att_src);
  k_abcd<<<306, 256, 0, stream>>>(Wv, Ws, Wl, bl, bs, bv, Wq, bq, Wk, bk,
                                  AB, cd, Wkt, vc, zero256);

  // GCN layers: agg (SpMM) + tiled GEMM, both XCD-partitioned, ping-pong
  int agrid = 8 * 24 * NCH_;        // 15744
  int ggrid = 8 * 122;              // 976 (122*64 covers 7800-row region)
  k_agg<CIN_><<<agrid, 256, 0, stream>>>(x, ptr_gcn, gcn_src, gcn_w, ag);
  k_gemm<CIN_, true, false, false><<<dim3(ggrid, 1), 256, 0, stream>>>(
      ag, ROWS_, Wg[0], bg[0], h0, Wg[0], bg[0], h0, 64, 64, 1, nullptr, nullptr);
  k_agg<H_><<<agrid, 256, 0, stream>>>(h0, ptr_gcn, gcn_src, gcn_w, ag);
  k_gemm<H_, true, false, false><<<dim3(ggrid, 1), 256, 0, stream>>>(
      ag, ROWS_, Wg[1], bg[1], h1, Wg[1], bg[1], h1, 64, 64, 1, nullptr, nullptr);
  k_agg<H_><<<agrid, 256, 0, stream>>>(h1, ptr_gcn, gcn_src, gcn_w, ag);
  k_gemm<H_, true, false, false><<<dim3(ggrid, 1), 256, 0, stream>>>(
      ag, ROWS_, Wg[2], bg[2], h0, Wg[2], bg[2], h0, 64, 64, 1, nullptr, nullptr);
  k_agg<H_><<<agrid, 256, 0, stream>>>(h0, ptr_gcn, gcn_src, gcn_w, ag);
  k_gemm<H_, true, false, false><<<dim3(ggrid, 1), 256, 0, stream>>>(
      ag, ROWS_, Wg[3], bg[3], h1, Wg[3], bg[3], h1, 64, 64, 1, nullptr, nullptr);

  // kt = xt @ Wkt over ALL rows (fp16 output); beta fused into epilogue
  k_gemm<H_, false, true, true><<<dim3(ggrid, 4), 256, 0, stream>>>(
      h1, ROWS_, Wkt, zero256, (float*)ktb, Wkt, zero256, (float*)ktb,
      QK_, QK_, 4, vc, bb);

  // attention + fin, single full-row XCD-aligned launches
  k_attn4<<<8 * (RPX_ / 4), 256, 0, stream>>>(ktb, h1, bb, ptr_att, att_src, zh);
  k_fin<<<8 * 24 * 11, 256, 0, stream>>>(zh, h1, AB, partial);

  k_red<<<(B_ * N_ * 12 + 255) / 256, 256, 0, stream>>>(partial, cd, ptr_att, y);
}